// Round 17
// baseline (93.675 us; speedup 1.0000x reference)
//
#include <hip/hip_runtime.h>

#define S_LEN 1024
#define EMB   1024
#define NH    16
#define HD    64
#define BATCH 4
#define M_TOT 4096                 // BATCH * S_LEN
#define QSZ   (BATCH * NH * S_LEN * HD)   // 4194304 elems per Q/K/V tensor

typedef __attribute__((ext_vector_type(4))) float  f32x4;
typedef __attribute__((ext_vector_type(8))) __bf16 bf16x8;

__device__ __forceinline__ unsigned short f2bf(float f) {
  union { float f; unsigned u; } a; a.f = f;
  unsigned r = a.u + 0x7fffu + ((a.u >> 16) & 1u);   // RNE
  return (unsigned short)(r >> 16);
}

__device__ __forceinline__ float fexp2(float x) {
#if __has_builtin(__builtin_amdgcn_exp2f)
  return __builtin_amdgcn_exp2f(x);
#else
  return exp2f(x);
#endif
}

// ---------- fused prep: x->bf16 + Wqkv^T->bf16 + Wproj^T->bf16 ----------
__global__ __launch_bounds__(256) void prep(
    const float* __restrict__ x, const float* __restrict__ Wqkv,
    const float* __restrict__ Wproj,
    unsigned short* __restrict__ xb, unsigned short* __restrict__ WqkvT,
    unsigned short* __restrict__ WprojT)
{
  __shared__ unsigned short tile[32][33];
  const int bid = blockIdx.x;
  if (bid < 4096) {
    const int i = bid * 256 + threadIdx.x;
    float4 v = ((const float4*)x)[i];
    ushort4 o;
    o.x = f2bf(v.x); o.y = f2bf(v.y); o.z = f2bf(v.z); o.w = f2bf(v.w);
    ((ushort4*)xb)[i] = o;
    return;
  }
  const float* in; unsigned short* out; int N, n0, k0;
  if (bid < 7168) {
    const int b2 = bid - 4096;
    in = Wqkv; out = WqkvT; N = 3 * EMB;
    n0 = (b2 % 96) * 32; k0 = (b2 / 96) * 32;
  } else {
    const int b3 = bid - 7168;
    in = Wproj; out = WprojT; N = EMB;
    n0 = (b3 % 32) * 32; k0 = (b3 / 32) * 32;
  }
  const int tx = threadIdx.x & 31, ty = threadIdx.x >> 5;
  #pragma unroll
  for (int r = ty; r < 32; r += 8)
    tile[r][tx] = f2bf(in[(size_t)(k0 + r) * N + n0 + tx]);
  __syncthreads();
  #pragma unroll
  for (int r = ty; r < 32; r += 8)
    out[(size_t)(n0 + r) * EMB + k0 + tx] = tile[tx][r];
}

// ========== gemm1: 256x128 tile, 8 waves (4Mx2N, 64x64/wave), BK=64 ======
// Fat wave-tiles cut LDS fragment duplication: A-frag read by 2 waves,
// B-frag by 4 -> 33 FLOP per LDS byte (vs 16 at 128x128/8w).
// 2-buf 96KB LDS (1 block/CU, 2 waves/SIMD); counted vmcnt(6) pipeline.
// XOR-swizzle chunk^=row&7 (pre-swizzled source, swizzled ds_read).
// EPI: Q/K scatter (b,h,s,d), Q pre-scaled 0.125*log2e; V -> LDS
//      transpose (128x264 tile) -> V^T (b,h,d,s).
__global__ __launch_bounds__(512, 2) void gemm_qkv(
    const unsigned short* __restrict__ A,
    const unsigned short* __restrict__ Bt,
    const float* __restrict__ bias,
    unsigned short* __restrict__ O)
{
  __shared__ alignas(16) char smem[98304];   // 2 bufs x (A 32K | B 16K)
  const int m0 = blockIdx.x * 256, n0 = blockIdx.y * 128;
  const int K = EMB;
  const int t = threadIdx.x;
  const int wid = t >> 6, lane = t & 63;
  const int wm = wid >> 1, wn = wid & 1;     // 4M x 2N waves, 64x64 each
  const int lr = lane & 15, lg = lane >> 4;
  const int nkt = K >> 6;                    // 16

  f32x4 acc[4][4] = {};

  auto STAGE = [&](int b, int kt) {
    const int k0 = kt << 6;
    char* dst = smem + b * 49152;
    #pragma unroll
    for (int l = 0; l < 4; ++l) {            // A: 32KB (256 rows x 128B)
      const int L = l * 8192 + t * 16;
      const int row = L >> 7, c = (L >> 4) & 7;
      const int ce = (c ^ (row & 7)) << 3;
      const unsigned short* gA = A + (size_t)(m0 + row) * K + k0 + ce;
      __builtin_amdgcn_global_load_lds(
          (const __attribute__((address_space(1))) unsigned int*)gA,
          (__attribute__((address_space(3))) unsigned int*)(dst + L),
          16, 0, 0);
    }
    #pragma unroll
    for (int l = 0; l < 2; ++l) {            // B: 16KB (128 rows x 128B)
      const int L = l * 8192 + t * 16;
      const int row = L >> 7, c = (L >> 4) & 7;
      const int ce = (c ^ (row & 7)) << 3;
      const unsigned short* gB = Bt + (size_t)(n0 + row) * K + k0 + ce;
      __builtin_amdgcn_global_load_lds(
          (const __attribute__((address_space(1))) unsigned int*)gB,
          (__attribute__((address_space(3))) unsigned int*)(dst + 32768 + L),
          16, 0, 0);
    }
  };

  STAGE(0, 0);

  for (int kt = 0; kt < nkt; ++kt) {
    const int cur = kt & 1;
    if (kt + 1 < nkt) {
      STAGE(cur ^ 1, kt + 1);
      asm volatile("s_waitcnt vmcnt(6)" ::: "memory");   // tile kt landed
    } else {
      asm volatile("s_waitcnt vmcnt(0)" ::: "memory");
    }
    __builtin_amdgcn_s_barrier();
    asm volatile("" ::: "memory");

    const char* Ab = smem + cur * 49152;
    const char* Bb = Ab + 32768;
    bf16x8 af[4][2], bfr[4][2];
    #pragma unroll
    for (int i = 0; i < 4; ++i)
      #pragma unroll
      for (int kk = 0; kk < 2; ++kk) {
        const int row = wm * 64 + i * 16 + lr;
        af[i][kk] = *(const bf16x8*)(Ab + row * 128 + (((kk * 4 + lg) ^ (row & 7)) << 4));
      }
    #pragma unroll
    for (int j = 0; j < 4; ++j)
      #pragma unroll
      for (int kk = 0; kk < 2; ++kk) {
        const int row = wn * 64 + j * 16 + lr;
        bfr[j][kk] = *(const bf16x8*)(Bb + row * 128 + (((kk * 4 + lg) ^ (row & 7)) << 4));
      }
    __builtin_amdgcn_s_setprio(1);
    #pragma unroll
    for (int i = 0; i < 4; ++i)
      #pragma unroll
      for (int j = 0; j < 4; ++j)
        #pragma unroll
        for (int kk = 0; kk < 2; ++kk)
          acc[i][j] = __builtin_amdgcn_mfma_f32_16x16x32_bf16(af[i][kk], bfr[j][kk], acc[i][j], 0, 0, 0);
    __builtin_amdgcn_s_setprio(0);

    asm volatile("s_waitcnt lgkmcnt(0)" ::: "memory");
    __builtin_amdgcn_s_barrier();
  }

  const int sec = n0 >> 10;                  // block-uniform: 0=Q 1=K 2=V
  if (sec < 2) {
    #pragma unroll
    for (int i = 0; i < 4; ++i)
      #pragma unroll
      for (int j = 0; j < 4; ++j) {
        const int col = n0 + wn * 64 + j * 16 + lr;
        const float bv = bias[col];
        const int cc = col & 1023, h = cc >> 6, d = cc & 63;
        #pragma unroll
        for (int r = 0; r < 4; ++r) {
          const int row = m0 + wm * 64 + i * 16 + lg * 4 + r;
          float v = acc[i][j][r] + bv;
          if (sec == 0) v *= 0.18033688f;    // 0.125 * log2(e)
          const int bb = row >> 10, ss = row & 1023;
          O[(size_t)sec * QSZ + (((size_t)(bb * NH + h) * S_LEN + ss) * HD + d)] = f2bf(v);
        }
      }
  } else {
    // V: transpose 256x128 tile through LDS [128 cols][264], write V^T
    unsigned short* T = (unsigned short*)smem;
    __syncthreads();
    #pragma unroll
    for (int i = 0; i < 4; ++i)
      #pragma unroll
      for (int j = 0; j < 4; ++j) {
        const int ci = wn * 64 + j * 16 + lr;            // col in tile 0..127
        const float bv = bias[n0 + ci];
        union { ushort4 s4; __bf16 b[4]; } pk;
        #pragma unroll
        for (int r = 0; r < 4; ++r) pk.b[r] = (__bf16)(acc[i][j][r] + bv);
        *(ushort4*)(T + ci * 264 + wm * 64 + i * 16 + lg * 4) = pk.s4;
      }
    __syncthreads();
    const int ci = t >> 2, part = t & 3;     // ci 0..127, part 0..3 (64 s each)
    const int cc = (n0 - 2048) + ci;
    const int h = cc >> 6, d = cc & 63;
    const int bb2 = m0 >> 10, sbase = m0 & 1023;
    unsigned short* dst = O + 2ull * QSZ +
        ((size_t)(bb2 * NH + h) * HD + d) * S_LEN + sbase + part * 64;
    #pragma unroll
    for (int u = 0; u < 8; ++u)
      *(bf16x8*)(dst + u * 8) = *(const bf16x8*)(T + ci * 264 + part * 64 + u * 8);
  }
}

// ========== gemm2 (proj): 128x64 tile, 8 waves (4Mx2N), BK=64 (R15) ======
__global__ __launch_bounds__(512, 4) void gemm_proj(
    const unsigned short* __restrict__ A,
    const unsigned short* __restrict__ Bt,
    const float* __restrict__ bias,
    float* __restrict__ Of)
{
  __shared__ alignas(16) char smem[49152];   // 2 bufs x (A 16K | B 8K)
  const int m0 = blockIdx.x * 128, n0 = blockIdx.y * 64;
  const int K = EMB;
  const int t = threadIdx.x;
  const int wid = t >> 6, lane = t & 63;
  const int wm = wid >> 1, wn = wid & 1;     // 4M x 2N waves, 32x32 each
  const int lr = lane & 15, lg = lane >> 4;
  const int nkt = K >> 6;                    // 16

  f32x4 acc[2][2] = {};

  auto STAGE = [&](int b, int kt) {
    const int k0 = kt << 6;
    char* dst = smem + b * 24576;
    #pragma unroll
    for (int l = 0; l < 2; ++l) {            // A: 16KB (128 rows x 128B)
      const int L = l * 8192 + t * 16;
      const int row = L >> 7, c = (L >> 4) & 7;
      const int ce = (c ^ (row & 7)) << 3;
      const unsigned short* gA = A + (size_t)(m0 + row) * K + k0 + ce;
      __builtin_amdgcn_global_load_lds(
          (const __attribute__((address_space(1))) unsigned int*)gA,
          (__attribute__((address_space(3))) unsigned int*)(dst + L),
          16, 0, 0);
    }
    {                                        // B: 8KB (64 rows x 128B)
      const int L = t * 16;
      const int row = L >> 7, c = (L >> 4) & 7;
      const int ce = (c ^ (row & 7)) << 3;
      const unsigned short* gB = Bt + (size_t)(n0 + row) * K + k0 + ce;
      __builtin_amdgcn_global_load_lds(
          (const __attribute__((address_space(1))) unsigned int*)gB,
          (__attribute__((address_space(3))) unsigned int*)(dst + 16384 + L),
          16, 0, 0);
    }
  };

  STAGE(0, 0);

  for (int kt = 0; kt < nkt; ++kt) {
    const int cur = kt & 1;
    if (kt + 1 < nkt) {
      STAGE(cur ^ 1, kt + 1);
      asm volatile("s_waitcnt vmcnt(3)" ::: "memory");   // tile kt landed
    } else {
      asm volatile("s_waitcnt vmcnt(0)" ::: "memory");
    }
    __builtin_amdgcn_s_barrier();
    asm volatile("" ::: "memory");

    const char* Ab = smem + cur * 24576;
    const char* Bb = Ab + 16384;
    bf16x8 af[2][2], bfr[2][2];
    #pragma unroll
    for (int i = 0; i < 2; ++i)
      #pragma unroll
      for (int kk = 0; kk < 2; ++kk) {
        const int row = wm * 32 + i * 16 + lr;
        af[i][kk] = *(const bf16x8*)(Ab + row * 128 + (((kk * 4 + lg) ^ (row & 7)) << 4));
      }
    #pragma unroll
    for (int j = 0; j < 2; ++j)
      #pragma unroll
      for (int kk = 0; kk < 2; ++kk) {
        const int row = wn * 32 + j * 16 + lr;
        bfr[j][kk] = *(const bf16x8*)(Bb + row * 128 + (((kk * 4 + lg) ^ (row & 7)) << 4));
      }
    __builtin_amdgcn_s_setprio(1);
    #pragma unroll
    for (int i = 0; i < 2; ++i)
      #pragma unroll
      for (int j = 0; j < 2; ++j)
        #pragma unroll
        for (int kk = 0; kk < 2; ++kk)
          acc[i][j] = __builtin_amdgcn_mfma_f32_16x16x32_bf16(af[i][kk], bfr[j][kk], acc[i][j], 0, 0, 0);
    __builtin_amdgcn_s_setprio(0);

    asm volatile("s_waitcnt lgkmcnt(0)" ::: "memory");
    __builtin_amdgcn_s_barrier();
  }

  #pragma unroll
  for (int i = 0; i < 2; ++i)
    #pragma unroll
    for (int j = 0; j < 2; ++j) {
      const int col = n0 + wn * 32 + j * 16 + lr;
      const float bv = bias[col];
      #pragma unroll
      for (int r = 0; r < 4; ++r) {
        const int row = m0 + wm * 32 + i * 16 + lg * 4 + r;
        Of[(size_t)row * EMB + col] = acc[i][j][r] + bv;
      }
    }
}

// ---------------- causal flash attention (R16 config, unchanged) --------
__device__ __forceinline__ void group_tile(
    const char* sb, const bf16x8 (&kf)[8], const bf16x8 (&qf)[2],
    int kt, int q0, bool diag, int lr, int lg,
    float& m, float& lp, f32x4 (&o)[4])
{
  f32x4 sacc[4] = {};
  __builtin_amdgcn_s_setprio(1);
  #pragma unroll
  for (int nt = 0; nt < 4; ++nt)
    #pragma unroll
    for (int kk = 0; kk < 2; ++kk)
      sacc[nt] = __builtin_amdgcn_mfma_f32_16x16x32_bf16(kf[nt * 2 + kk], qf[kk], sacc[nt], 0, 0, 0);
  __builtin_amdgcn_s_setprio(0);

  float p[16];
  if (diag) {
    const int q = q0 + lr;
    #pragma unroll
    for (int nt = 0; nt < 4; ++nt)
      #pragma unroll
      for (int r = 0; r < 4; ++r) {
        int k = kt * 64 + nt * 16 + lg * 4 + r;
        p[nt * 4 + r] = (k > q) ? -1e30f : sacc[nt][r];
      }
  } else {
    #pragma unroll
    for (int nt = 0; nt < 4; ++nt)
      #pragma unroll
      for (int r = 0; r < 4; ++r)
        p[nt * 4 + r] = sacc[nt][r];
  }

  float r8[8], r4[4];
  #pragma unroll
  for (int i = 0; i < 8; ++i) r8[i] = fmaxf(p[i], p[i + 8]);
  #pragma unroll
  for (int i = 0; i < 4; ++i) r4[i] = fmaxf(r8[i], r8[i + 4]);
  float pm = fmaxf(fmaxf(r4[0], r4[1]), fmaxf(r4[2], r4[3]));
  if (__any(pm > m + 11.5f)) {
    float px = fmaxf(pm, __shfl_xor(pm, 16, 64));
    px = fmaxf(px, __shfl_xor(px, 32, 64));
    float mn = fmaxf(m, px);
    float fs = fexp2(m - mn);
    lp *= fs;
    #pragma unroll
    for (int dt = 0; dt < 4; ++dt)
      #pragma unroll
      for (int r = 0; r < 4; ++r) o[dt][r] *= fs;
    m = mn;
  }
  #pragma unroll
  for (int i = 0; i < 16; ++i) p[i] = fexp2(p[i] - m);

  float s8[8], s4[4];
  #pragma unroll
  for (int i = 0; i < 8; ++i) s8[i] = p[i] + p[i + 8];
  #pragma unroll
  for (int i = 0; i < 4; ++i) s4[i] = s8[i] + s8[i + 4];
  lp += (s4[0] + s4[1]) + (s4[2] + s4[3]);

  union { unsigned u[8]; __bf16 b[16]; } W;
  #pragma unroll
  for (int i = 0; i < 16; ++i) W.b[i] = (__bf16)p[i];

  const int dl0 = ((2 * (lg & 1) + (lg >> 1)) * 16 + lr) << 2;
  const int dl1 = ((2 * ((lg & 1) ^ 1) + (lg >> 1)) * 16 + lr) << 2;
  const bool oddlg = (lg & 1) != 0;
  const bool hb    = (lg >> 1) != 0;
  union { unsigned u[4]; bf16x8 v; } T0, T1;
  #pragma unroll
  for (int kk = 0; kk < 2; ++kk) {
    #pragma unroll
    for (int c = 0; c < 2; ++c) {
      unsigned vlo = W.u[4 * kk + c];
      unsigned vhi = W.u[4 * kk + 2 + c];
      unsigned s0 = oddlg ? vhi : vlo;
      unsigned s1 = oddlg ? vlo : vhi;
      unsigned r0 = (unsigned)__builtin_amdgcn_ds_permute(dl0, (int)s0);
      unsigned r1 = (unsigned)__builtin_amdgcn_ds_permute(dl1, (int)s1);
      unsigned* T = kk ? T1.u : T0.u;
      T[c]     = hb ? r1 : r0;
      T[2 + c] = hb ? r0 : r1;
    }
  }

  // PV: stream V^T fragments from LDS (16 regs at a time, keeps VGPR low)
  __builtin_amdgcn_s_setprio(1);
  #pragma unroll
  for (int dt = 0; dt < 4; ++dt) {
    const int byt = (dt * 16 + lr) * 128;
    bf16x8 v0 = *(const bf16x8*)(sb + 8192 + byt + (((0 + lg) ^ (lr & 7)) << 4));
    bf16x8 v1 = *(const bf16x8*)(sb + 8192 + byt + (((4 + lg) ^ (lr & 7)) << 4));
    o[dt] = __builtin_amdgcn_mfma_f32_16x16x32_bf16(v0, T0.v, o[dt], 0, 0, 0);
    o[dt] = __builtin_amdgcn_mfma_f32_16x16x32_bf16(v1, T1.v, o[dt], 0, 0, 0);
  }
  __builtin_amdgcn_s_setprio(0);
}

__global__ __launch_bounds__(256, 4) void attn_fwd(
    const unsigned short* __restrict__ Q,
    const unsigned short* __restrict__ K,
    const unsigned short* __restrict__ Vt,
    unsigned short* __restrict__ attout)
{
  __shared__ alignas(16) char stage[2][16384];   // 2-buf: K 8KB | V^T 8KB
  __shared__ alignas(16) char Ep_lds[4][2048];
  const int bid = blockIdx.x;
  const int bh = ((bid & 7) << 3) | ((bid >> 3) & 7);   // head; 16 blocks/head on 1 XCD
  const int qt = 15 - (bid >> 6);                       // heavy chunks first
  const int wv = threadIdx.x >> 6, lane = threadIdx.x & 63;
  const int lr = lane & 15, lg = lane >> 4;
  const int q0 = qt * 64 + wv * 16;
  const int nkt = qt + 1;
  const unsigned short* Qb = Q  + (size_t)bh * (S_LEN * HD);
  const unsigned short* Kh = K  + (size_t)bh * (S_LEN * HD);
  const unsigned short* Vh = Vt + (size_t)bh * (HD * S_LEN);
  const int bb = bh >> 4, h = bh & 15;

  auto STAGE = [&](int b, int kt) {
    char* lb = &stage[b][0];
    #pragma unroll
    for (int j = 0; j < 4; ++j) {
      if (wv < 2) {
        int L = wv * 4096 + j * 1024 + lane * 16;
        int row = L >> 7, c = (L >> 4) & 7;
        const unsigned short* src = Kh + (size_t)(kt * 64 + row) * HD + ((c ^ (row & 7)) << 3);
        __builtin_amdgcn_global_load_lds(
            (const __attribute__((address_space(1))) unsigned int*)src,
            (__attribute__((address_space(3))) unsigned int*)(lb + wv * 4096 + j * 1024),
            16, 0, 0);
      } else {
        int L = (wv - 2) * 4096 + j * 1024 + lane * 16;
        int row = L >> 7, c = (L >> 4) & 7;
        const unsigned short* src = Vh + (size_t)row * S_LEN + kt * 64 + ((c ^ (row & 7)) << 3);
        __builtin_amdgcn_global_load_lds(
            (const __attribute__((address_space(1))) unsigned int*)src,
            (__attribute__((address_space(3))) unsigned int*)(lb + 8192 + (wv - 2) * 4096 + j * 1024),
            16, 0, 0);
      }
    }
  };

  bf16x8 qf[2];
  #pragma unroll
  for (int kk = 0; kk < 2; ++kk)
    qf[kk] = *(const bf16x8*)(Qb + (size_t)(q0 + lr) * HD + kk * 32 + lg * 8);

  float m = -1e30f, lp = 0.f;
  f32x4 o[4] = {};

  STAGE(0, 0);

  for (int kt = 0; kt < nkt; ++kt) {
    asm volatile("s_waitcnt vmcnt(0)" ::: "memory");     // tile kt landed
    __builtin_amdgcn_s_barrier();
    asm volatile("" ::: "memory");

    const char* sb = &stage[kt & 1][0];
    bf16x8 kf[8];
    #pragma unroll
    for (int nt = 0; nt < 4; ++nt)
      #pragma unroll
      for (int kk = 0; kk < 2; ++kk) {
        const int byt = (nt * 16 + lr) * 128 + ((((kk << 2) + lg) ^ (lr & 7)) << 4);
        kf[nt * 2 + kk] = *(const bf16x8*)(sb + byt);
      }
    if (kt + 1 < nkt) STAGE((kt + 1) & 1, kt + 1);       // other buffer

    group_tile(sb, kf, qf, kt, q0, kt == nkt - 1, lr, lg, m, lp, o);

    asm volatile("s_waitcnt lgkmcnt(0)" ::: "memory");   // my reads done
    __builtin_amdgcn_s_barrier();
  }

  // epilogue: O^T[d][q] -> LDS (swizzled) -> coalesced (q, d) stores
  float l2 = lp + __shfl_xor(lp, 16, 64);
  float l4 = l2 + __shfl_xor(l2, 32, 64);
  float rl = 1.0f / l4;
  char* Ep = &Ep_lds[wv][0];
  #pragma unroll
  for (int dt = 0; dt < 4; ++dt) {
    union { ushort4 s4; __bf16 b[4]; } ov;
    #pragma unroll
    for (int r = 0; r < 4; ++r) ov.b[r] = (__bf16)(o[dt][r] * rl);
    int byt = (lr * 128 + (dt * 16 + lg * 4) * 2) ^ ((lr & 7) << 4);
    *(ushort4*)(Ep + byt) = ov.s4;
  }
  asm volatile("s_waitcnt lgkmcnt(0)" ::: "memory");
  const int lane2 = lr + lg * 16;
  const int ql = lane2 >> 2, c = lane2 & 3;
  #pragma unroll
  for (int s = 0; s < 2; ++s) {
    int byt = (ql * 128 + (c * 16 + s * 8) * 2) ^ ((ql & 7) << 4);
    bf16x8 vrow = *(const bf16x8*)(Ep + byt);
    *(bf16x8*)(attout + (size_t)(bb * S_LEN + q0 + ql) * EMB + h * HD + c * 16 + s * 8) = vrow;
  }
}

extern "C" void kernel_launch(void* const* d_in, const int* in_sizes, int n_in,
                              void* d_out, int out_size, void* d_ws, size_t ws_size,
                              hipStream_t stream) {
  const float* x     = (const float*)d_in[0];
  const float* Wqkv  = (const float*)d_in[1];
  const float* bqkv  = (const float*)d_in[2];
  const float* Wproj = (const float*)d_in[3];
  const float* bproj = (const float*)d_in[4];

  unsigned short* xb     = (unsigned short*)d_ws;                  // 4096*1024 x bf16
  unsigned short* WqkvT  = xb     + (size_t)M_TOT * EMB;           // 3072*1024
  unsigned short* WprojT = WqkvT  + (size_t)3 * EMB * EMB;         // 1024*1024
  unsigned short* qkv    = WprojT + (size_t)EMB * EMB;             // Q,K (b,h,s,d); V^T (b,h,d,s)
  unsigned short* att    = qkv    + 3ull * QSZ;                    // 4096*1024

  prep<<<dim3(8192), dim3(256), 0, stream>>>(x, Wqkv, Wproj, xb, WqkvT, WprojT);

  gemm_qkv<<<dim3(M_TOT / 256, 3 * EMB / 128), dim3(512), 0, stream>>>(
      xb, WqkvT, bqkv, qkv);

  attn_fwd<<<dim3(16 * BATCH * NH), dim3(256), 0, stream>>>(
      qkv, qkv + QSZ, qkv + 2ull * QSZ, att);

  gemm_proj<<<dim3(M_TOT / 128, EMB / 64), dim3(512), 0, stream>>>(
      att, WprojT, bproj, (float*)d_out);
}

// Round 18
// 92.965 us; speedup vs baseline: 1.0076x; 1.0076x over previous
//
#include <hip/hip_runtime.h>

#define S_LEN 1024
#define EMB   1024
#define NH    16
#define HD    64
#define BATCH 4
#define M_TOT 4096                 // BATCH * S_LEN
#define QSZ   (BATCH * NH * S_LEN * HD)   // 4194304 elems per Q/K/V tensor

typedef __attribute__((ext_vector_type(4))) float  f32x4;
typedef __attribute__((ext_vector_type(8))) __bf16 bf16x8;

__device__ __forceinline__ unsigned short f2bf(float f) {
  union { float f; unsigned u; } a; a.f = f;
  unsigned r = a.u + 0x7fffu + ((a.u >> 16) & 1u);   // RNE
  return (unsigned short)(r >> 16);
}

__device__ __forceinline__ float fexp2(float x) {
#if __has_builtin(__builtin_amdgcn_exp2f)
  return __builtin_amdgcn_exp2f(x);
#else
  return exp2f(x);
#endif
}

// ---------- prep: Wqkv^T->bf16 + Wproj^T->bf16 (x-cvt fused into gemm1) --
__global__ __launch_bounds__(256) void prep(
    const float* __restrict__ Wqkv, const float* __restrict__ Wproj,
    unsigned short* __restrict__ WqkvT, unsigned short* __restrict__ WprojT)
{
  __shared__ unsigned short tile[32][33];
  const int bid = blockIdx.x;
  const float* in; unsigned short* out; int N, n0, k0;
  if (bid < 3072) {
    in = Wqkv; out = WqkvT; N = 3 * EMB;
    n0 = (bid % 96) * 32; k0 = (bid / 96) * 32;
  } else {
    const int b3 = bid - 3072;
    in = Wproj; out = WprojT; N = EMB;
    n0 = (b3 % 32) * 32; k0 = (b3 / 32) * 32;
  }
  const int tx = threadIdx.x & 31, ty = threadIdx.x >> 5;
  #pragma unroll
  for (int r = ty; r < 32; r += 8)
    tile[r][tx] = f2bf(in[(size_t)(k0 + r) * N + n0 + tx]);
  __syncthreads();
  #pragma unroll
  for (int r = ty; r < 32; r += 8)
    out[(size_t)(n0 + r) * EMB + k0 + tx] = tile[tx][r];
}

// ========== gemm1: 128x128 tile, 8 waves (2Mx4N), BK=64 ==================
// A sourced DIRECTLY from fp32 x: reg-staged (4x float4 issued at iter
// top, cvt+ds_write after MFMA) -> kills the separate x-cvt pass.
// B via global_load_lds. Counted waits: A issued first, B second ->
// top-of-iter vmcnt(6) = B(kt) landed; compiler waits A-regs before cvt.
// 2-buf 64KB LDS, 2 blocks/CU. XOR-swizzle chunk^=row&7 both sides.
// EPI: Q/K scatter (b,h,s,d), Q pre-scaled 0.125*log2e; V -> LDS
//      transpose -> V^T (b,h,d,s).
__global__ __launch_bounds__(512, 4) void gemm_qkv(
    const float* __restrict__ X,
    const unsigned short* __restrict__ Bt,
    const float* __restrict__ bias,
    unsigned short* __restrict__ O)
{
  __shared__ alignas(16) char smem[65536];   // [buf][A 16K | B 16K]
  const int m0 = blockIdx.x * 128, n0 = blockIdx.y * 128;
  const int K = EMB;
  const int t = threadIdx.x;
  const int wid = t >> 6, lane = t & 63;
  const int wm = wid >> 2, wn = wid & 3;     // 2 x 4 waves
  const int lr = lane & 15, lg = lane >> 4;
  const int nkt = K >> 6;                    // 16

  f32x4 acc[4][2] = {};

  // per-thread A-chunk coordinates (two 16B bf16 chunks)
  int arow[2], ace[2];
  #pragma unroll
  for (int l = 0; l < 2; ++l) {
    const int L = l * 8192 + t * 16;
    arow[l] = L >> 7;
    ace[l]  = (((L >> 4) & 7) ^ (arow[l] & 7)) << 3;
  }

  auto ISSUE_A = [&](int kt, float4* av) {     // 4x float4 (32B per chunk)
    const int k0 = kt << 6;
    #pragma unroll
    for (int l = 0; l < 2; ++l) {
      const float* src = X + (size_t)(m0 + arow[l]) * K + k0 + ace[l];
      av[l * 2 + 0] = ((const float4*)src)[0];
      av[l * 2 + 1] = ((const float4*)src)[1];
    }
  };
  auto ISSUE_B = [&](int b, int kt) {
    const int k0 = kt << 6;
    #pragma unroll
    for (int l = 0; l < 2; ++l) {
      const int L = l * 8192 + t * 16;
      const int row = L >> 7, c = (L >> 4) & 7;
      const int ce = (c ^ (row & 7)) << 3;
      const unsigned short* gB = Bt + (size_t)(n0 + row) * K + k0 + ce;
      __builtin_amdgcn_global_load_lds(
          (const __attribute__((address_space(1))) unsigned int*)gB,
          (__attribute__((address_space(3))) unsigned int*)(smem + b * 32768 + 16384 + L),
          16, 0, 0);
    }
  };
  auto WRITE_A = [&](int b, const float4* av) {
    #pragma unroll
    for (int l = 0; l < 2; ++l) {
      union { bf16x8 v; unsigned short s[8]; } pk;
      #pragma unroll
      for (int e = 0; e < 4; ++e) {
        pk.s[e]     = f2bf(av[l * 2 + 0][e]);
        pk.s[e + 4] = f2bf(av[l * 2 + 1][e]);
      }
      *(bf16x8*)(smem + b * 32768 + l * 8192 + t * 16) = pk.v;
    }
  };

  // prologue: stage tile 0
  {
    float4 av[4];
    ISSUE_A(0, av);
    ISSUE_B(0, 0);
    WRITE_A(0, av);                          // compiler waits the 4 loads
    asm volatile("s_waitcnt vmcnt(0) lgkmcnt(0)" ::: "memory");
    __builtin_amdgcn_s_barrier();
  }

  for (int kt = 0; kt < nkt; ++kt) {
    const int cur = kt & 1;
    float4 av[4];
    if (kt + 1 < nkt) {
      ISSUE_A(kt + 1, av);                   // 4 reg loads (oldest batch)
      ISSUE_B(cur ^ 1, kt + 1);              // 2 gload_lds
      asm volatile("s_waitcnt vmcnt(6)" ::: "memory");   // B(kt) landed
    } else {
      asm volatile("s_waitcnt vmcnt(0)" ::: "memory");
    }
    __builtin_amdgcn_s_barrier();
    asm volatile("" ::: "memory");

    const char* Ab = smem + cur * 32768;
    const char* Bb = Ab + 16384;
    bf16x8 af[4][2], bfr[2][2];
    #pragma unroll
    for (int i = 0; i < 4; ++i)
      #pragma unroll
      for (int kk = 0; kk < 2; ++kk) {
        const int row = wm * 64 + i * 16 + lr;
        af[i][kk] = *(const bf16x8*)(Ab + row * 128 + (((kk * 4 + lg) ^ (row & 7)) << 4));
      }
    #pragma unroll
    for (int j = 0; j < 2; ++j)
      #pragma unroll
      for (int kk = 0; kk < 2; ++kk) {
        const int row = wn * 32 + j * 16 + lr;
        bfr[j][kk] = *(const bf16x8*)(Bb + row * 128 + (((kk * 4 + lg) ^ (row & 7)) << 4));
      }
    __builtin_amdgcn_s_setprio(1);
    #pragma unroll
    for (int i = 0; i < 4; ++i)
      #pragma unroll
      for (int j = 0; j < 2; ++j)
        #pragma unroll
        for (int kk = 0; kk < 2; ++kk)
          acc[i][j] = __builtin_amdgcn_mfma_f32_16x16x32_bf16(af[i][kk], bfr[j][kk], acc[i][j], 0, 0, 0);
    __builtin_amdgcn_s_setprio(0);

    if (kt + 1 < nkt)
      WRITE_A(cur ^ 1, av);                  // buf nxt free since iter kt-1

    asm volatile("s_waitcnt lgkmcnt(0)" ::: "memory");   // reads+writes done
    __builtin_amdgcn_s_barrier();
  }

  const int sec = n0 >> 10;                  // block-uniform: 0=Q 1=K 2=V
  if (sec < 2) {
    #pragma unroll
    for (int i = 0; i < 4; ++i)
      #pragma unroll
      for (int j = 0; j < 2; ++j) {
        const int col = n0 + wn * 32 + j * 16 + lr;
        const float bv = bias[col];
        const int cc = col & 1023, h = cc >> 6, d = cc & 63;
        #pragma unroll
        for (int r = 0; r < 4; ++r) {
          const int row = m0 + wm * 64 + i * 16 + lg * 4 + r;
          float v = acc[i][j][r] + bv;
          if (sec == 0) v *= 0.18033688f;    // 0.125 * log2(e)
          const int bb = row >> 10, ss = row & 1023;
          O[(size_t)sec * QSZ + (((size_t)(bb * NH + h) * S_LEN + ss) * HD + d)] = f2bf(v);
        }
      }
  } else {
    // V: transpose 128x128 tile through LDS, write V^T (b,h,d,s)
    unsigned short* T = (unsigned short*)smem;           // [128][136]
    #pragma unroll
    for (int i = 0; i < 4; ++i)
      #pragma unroll
      for (int j = 0; j < 2; ++j) {
        const int ci = wn * 32 + j * 16 + lr;            // col in tile
        const float bv = bias[n0 + ci];
        union { ushort4 s4; __bf16 b[4]; } pk;
        #pragma unroll
        for (int r = 0; r < 4; ++r) pk.b[r] = (__bf16)(acc[i][j][r] + bv);
        *(ushort4*)(T + ci * 136 + wm * 64 + i * 16 + lg * 4) = pk.s4;
      }
    __syncthreads();
    const int ci = t >> 2, part = t & 3;
    const int cc = (n0 - 2048) + ci;
    const int h = cc >> 6, d = cc & 63;
    const int bb2 = m0 >> 10, sbase = m0 & 1023;
    unsigned short* dst = O + 2ull * QSZ +
        ((size_t)(bb2 * NH + h) * HD + d) * S_LEN + sbase;
    #pragma unroll
    for (int u = 0; u < 4; ++u) {
      const int spos = part * 32 + u * 8;
      *(bf16x8*)(dst + spos) = *(const bf16x8*)(T + ci * 136 + spos);
    }
  }
}

// ========== gemm2 (proj): 128x64 tile, 8 waves (4Mx2N), BK=64 (R15) ======
__global__ __launch_bounds__(512, 4) void gemm_proj(
    const unsigned short* __restrict__ A,
    const unsigned short* __restrict__ Bt,
    const float* __restrict__ bias,
    float* __restrict__ Of)
{
  __shared__ alignas(16) char smem[49152];   // 2 bufs x (A 16K | B 8K)
  const int m0 = blockIdx.x * 128, n0 = blockIdx.y * 64;
  const int K = EMB;
  const int t = threadIdx.x;
  const int wid = t >> 6, lane = t & 63;
  const int wm = wid >> 1, wn = wid & 1;     // 4M x 2N waves, 32x32 each
  const int lr = lane & 15, lg = lane >> 4;
  const int nkt = K >> 6;                    // 16

  f32x4 acc[2][2] = {};

  auto STAGE = [&](int b, int kt) {
    const int k0 = kt << 6;
    char* dst = smem + b * 24576;
    #pragma unroll
    for (int l = 0; l < 2; ++l) {            // A: 16KB (128 rows x 128B)
      const int L = l * 8192 + t * 16;
      const int row = L >> 7, c = (L >> 4) & 7;
      const int ce = (c ^ (row & 7)) << 3;
      const unsigned short* gA = A + (size_t)(m0 + row) * K + k0 + ce;
      __builtin_amdgcn_global_load_lds(
          (const __attribute__((address_space(1))) unsigned int*)gA,
          (__attribute__((address_space(3))) unsigned int*)(dst + L),
          16, 0, 0);
    }
    {                                        // B: 8KB (64 rows x 128B)
      const int L = t * 16;
      const int row = L >> 7, c = (L >> 4) & 7;
      const int ce = (c ^ (row & 7)) << 3;
      const unsigned short* gB = Bt + (size_t)(n0 + row) * K + k0 + ce;
      __builtin_amdgcn_global_load_lds(
          (const __attribute__((address_space(1))) unsigned int*)gB,
          (__attribute__((address_space(3))) unsigned int*)(dst + 16384 + L),
          16, 0, 0);
    }
  };

  STAGE(0, 0);

  for (int kt = 0; kt < nkt; ++kt) {
    const int cur = kt & 1;
    if (kt + 1 < nkt) {
      STAGE(cur ^ 1, kt + 1);
      asm volatile("s_waitcnt vmcnt(3)" ::: "memory");   // tile kt landed
    } else {
      asm volatile("s_waitcnt vmcnt(0)" ::: "memory");
    }
    __builtin_amdgcn_s_barrier();
    asm volatile("" ::: "memory");

    const char* Ab = smem + cur * 24576;
    const char* Bb = Ab + 16384;
    bf16x8 af[2][2], bfr[2][2];
    #pragma unroll
    for (int i = 0; i < 2; ++i)
      #pragma unroll
      for (int kk = 0; kk < 2; ++kk) {
        const int row = wm * 32 + i * 16 + lr;
        af[i][kk] = *(const bf16x8*)(Ab + row * 128 + (((kk * 4 + lg) ^ (row & 7)) << 4));
      }
    #pragma unroll
    for (int j = 0; j < 2; ++j)
      #pragma unroll
      for (int kk = 0; kk < 2; ++kk) {
        const int row = wn * 32 + j * 16 + lr;
        bfr[j][kk] = *(const bf16x8*)(Bb + row * 128 + (((kk * 4 + lg) ^ (row & 7)) << 4));
      }
    __builtin_amdgcn_s_setprio(1);
    #pragma unroll
    for (int i = 0; i < 2; ++i)
      #pragma unroll
      for (int j = 0; j < 2; ++j)
        #pragma unroll
        for (int kk = 0; kk < 2; ++kk)
          acc[i][j] = __builtin_amdgcn_mfma_f32_16x16x32_bf16(af[i][kk], bfr[j][kk], acc[i][j], 0, 0, 0);
    __builtin_amdgcn_s_setprio(0);

    asm volatile("s_waitcnt lgkmcnt(0)" ::: "memory");
    __builtin_amdgcn_s_barrier();
  }

  #pragma unroll
  for (int i = 0; i < 2; ++i)
    #pragma unroll
    for (int j = 0; j < 2; ++j) {
      const int col = n0 + wn * 32 + j * 16 + lr;
      const float bv = bias[col];
      #pragma unroll
      for (int r = 0; r < 4; ++r) {
        const int row = m0 + wm * 32 + i * 16 + lg * 4 + r;
        Of[(size_t)row * EMB + col] = acc[i][j][r] + bv;
      }
    }
}

// ---------------- causal flash attention (R16 config, unchanged) --------
__device__ __forceinline__ void group_tile(
    const char* sb, const bf16x8 (&kf)[8], const bf16x8 (&qf)[2],
    int kt, int q0, bool diag, int lr, int lg,
    float& m, float& lp, f32x4 (&o)[4])
{
  f32x4 sacc[4] = {};
  __builtin_amdgcn_s_setprio(1);
  #pragma unroll
  for (int nt = 0; nt < 4; ++nt)
    #pragma unroll
    for (int kk = 0; kk < 2; ++kk)
      sacc[nt] = __builtin_amdgcn_mfma_f32_16x16x32_bf16(kf[nt * 2 + kk], qf[kk], sacc[nt], 0, 0, 0);
  __builtin_amdgcn_s_setprio(0);

  float p[16];
  if (diag) {
    const int q = q0 + lr;
    #pragma unroll
    for (int nt = 0; nt < 4; ++nt)
      #pragma unroll
      for (int r = 0; r < 4; ++r) {
        int k = kt * 64 + nt * 16 + lg * 4 + r;
        p[nt * 4 + r] = (k > q) ? -1e30f : sacc[nt][r];
      }
  } else {
    #pragma unroll
    for (int nt = 0; nt < 4; ++nt)
      #pragma unroll
      for (int r = 0; r < 4; ++r)
        p[nt * 4 + r] = sacc[nt][r];
  }

  float r8[8], r4[4];
  #pragma unroll
  for (int i = 0; i < 8; ++i) r8[i] = fmaxf(p[i], p[i + 8]);
  #pragma unroll
  for (int i = 0; i < 4; ++i) r4[i] = fmaxf(r8[i], r8[i + 4]);
  float pm = fmaxf(fmaxf(r4[0], r4[1]), fmaxf(r4[2], r4[3]));
  if (__any(pm > m + 11.5f)) {
    float px = fmaxf(pm, __shfl_xor(pm, 16, 64));
    px = fmaxf(px, __shfl_xor(px, 32, 64));
    float mn = fmaxf(m, px);
    float fs = fexp2(m - mn);
    lp *= fs;
    #pragma unroll
    for (int dt = 0; dt < 4; ++dt)
      #pragma unroll
      for (int r = 0; r < 4; ++r) o[dt][r] *= fs;
    m = mn;
  }
  #pragma unroll
  for (int i = 0; i < 16; ++i) p[i] = fexp2(p[i] - m);

  float s8[8], s4[4];
  #pragma unroll
  for (int i = 0; i < 8; ++i) s8[i] = p[i] + p[i + 8];
  #pragma unroll
  for (int i = 0; i < 4; ++i) s4[i] = s8[i] + s8[i + 4];
  lp += (s4[0] + s4[1]) + (s4[2] + s4[3]);

  union { unsigned u[8]; __bf16 b[16]; } W;
  #pragma unroll
  for (int i = 0; i < 16; ++i) W.b[i] = (__bf16)p[i];

  const int dl0 = ((2 * (lg & 1) + (lg >> 1)) * 16 + lr) << 2;
  const int dl1 = ((2 * ((lg & 1) ^ 1) + (lg >> 1)) * 16 + lr) << 2;
  const bool oddlg = (lg & 1) != 0;
  const bool hb    = (lg >> 1) != 0;
  union { unsigned u[4]; bf16x8 v; } T0, T1;
  #pragma unroll
  for (int kk = 0; kk < 2; ++kk) {
    #pragma unroll
    for (int c = 0; c < 2; ++c) {
      unsigned vlo = W.u[4 * kk + c];
      unsigned vhi = W.u[4 * kk + 2 + c];
      unsigned s0 = oddlg ? vhi : vlo;
      unsigned s1 = oddlg ? vlo : vhi;
      unsigned r0 = (unsigned)__builtin_amdgcn_ds_permute(dl0, (int)s0);
      unsigned r1 = (unsigned)__builtin_amdgcn_ds_permute(dl1, (int)s1);
      unsigned* T = kk ? T1.u : T0.u;
      T[c]     = hb ? r1 : r0;
      T[2 + c] = hb ? r0 : r1;
    }
  }

  // PV: stream V^T fragments from LDS (16 regs at a time, keeps VGPR low)
  __builtin_amdgcn_s_setprio(1);
  #pragma unroll
  for (int dt = 0; dt < 4; ++dt) {
    const int byt = (dt * 16 + lr) * 128;
    bf16x8 v0 = *(const bf16x8*)(sb + 8192 + byt + (((0 + lg) ^ (lr & 7)) << 4));
    bf16x8 v1 = *(const bf16x8*)(sb + 8192 + byt + (((4 + lg) ^ (lr & 7)) << 4));
    o[dt] = __builtin_amdgcn_mfma_f32_16x16x32_bf16(v0, T0.v, o[dt], 0, 0, 0);
    o[dt] = __builtin_amdgcn_mfma_f32_16x16x32_bf16(v1, T1.v, o[dt], 0, 0, 0);
  }
  __builtin_amdgcn_s_setprio(0);
}

__global__ __launch_bounds__(256, 4) void attn_fwd(
    const unsigned short* __restrict__ Q,
    const unsigned short* __restrict__ K,
    const unsigned short* __restrict__ Vt,
    unsigned short* __restrict__ attout)
{
  __shared__ alignas(16) char stage[2][16384];   // 2-buf: K 8KB | V^T 8KB
  __shared__ alignas(16) char Ep_lds[4][2048];
  const int bid = blockIdx.x;
  const int bh = ((bid & 7) << 3) | ((bid >> 3) & 7);   // head; 16 blocks/head on 1 XCD
  const int qt = 15 - (bid >> 6);                       // heavy chunks first
  const int wv = threadIdx.x >> 6, lane = threadIdx.x & 63;
  const int lr = lane & 15, lg = lane >> 4;
  const int q0 = qt * 64 + wv * 16;
  const int nkt = qt + 1;
  const unsigned short* Qb = Q  + (size_t)bh * (S_LEN * HD);
  const unsigned short* Kh = K  + (size_t)bh * (S_LEN * HD);
  const unsigned short* Vh = Vt + (size_t)bh * (HD * S_LEN);
  const int bb = bh >> 4, h = bh & 15;

  auto STAGE = [&](int b, int kt) {
    char* lb = &stage[b][0];
    #pragma unroll
    for (int j = 0; j < 4; ++j) {
      if (wv < 2) {
        int L = wv * 4096 + j * 1024 + lane * 16;
        int row = L >> 7, c = (L >> 4) & 7;
        const unsigned short* src = Kh + (size_t)(kt * 64 + row) * HD + ((c ^ (row & 7)) << 3);
        __builtin_amdgcn_global_load_lds(
            (const __attribute__((address_space(1))) unsigned int*)src,
            (__attribute__((address_space(3))) unsigned int*)(lb + wv * 4096 + j * 1024),
            16, 0, 0);
      } else {
        int L = (wv - 2) * 4096 + j * 1024 + lane * 16;
        int row = L >> 7, c = (L >> 4) & 7;
        const unsigned short* src = Vh + (size_t)row * S_LEN + kt * 64 + ((c ^ (row & 7)) << 3);
        __builtin_amdgcn_global_load_lds(
            (const __attribute__((address_space(1))) unsigned int*)src,
            (__attribute__((address_space(3))) unsigned int*)(lb + 8192 + (wv - 2) * 4096 + j * 1024),
            16, 0, 0);
      }
    }
  };

  bf16x8 qf[2];
  #pragma unroll
  for (int kk = 0; kk < 2; ++kk)
    qf[kk] = *(const bf16x8*)(Qb + (size_t)(q0 + lr) * HD + kk * 32 + lg * 8);

  float m = -1e30f, lp = 0.f;
  f32x4 o[4] = {};

  STAGE(0, 0);

  for (int kt = 0; kt < nkt; ++kt) {
    asm volatile("s_waitcnt vmcnt(0)" ::: "memory");     // tile kt landed
    __builtin_amdgcn_s_barrier();
    asm volatile("" ::: "memory");

    const char* sb = &stage[kt & 1][0];
    bf16x8 kf[8];
    #pragma unroll
    for (int nt = 0; nt < 4; ++nt)
      #pragma unroll
      for (int kk = 0; kk < 2; ++kk) {
        const int byt = (nt * 16 + lr) * 128 + ((((kk << 2) + lg) ^ (lr & 7)) << 4);
        kf[nt * 2 + kk] = *(const bf16x8*)(sb + byt);
      }
    if (kt + 1 < nkt) STAGE((kt + 1) & 1, kt + 1);       // other buffer

    group_tile(sb, kf, qf, kt, q0, kt == nkt - 1, lr, lg, m, lp, o);

    asm volatile("s_waitcnt lgkmcnt(0)" ::: "memory");   // my reads done
    __builtin_amdgcn_s_barrier();
  }

  // epilogue: O^T[d][q] -> LDS (swizzled) -> coalesced (q, d) stores
  float l2 = lp + __shfl_xor(lp, 16, 64);
  float l4 = l2 + __shfl_xor(l2, 32, 64);
  float rl = 1.0f / l4;
  char* Ep = &Ep_lds[wv][0];
  #pragma unroll
  for (int dt = 0; dt < 4; ++dt) {
    union { ushort4 s4; __bf16 b[4]; } ov;
    #pragma unroll
    for (int r = 0; r < 4; ++r) ov.b[r] = (__bf16)(o[dt][r] * rl);
    int byt = (lr * 128 + (dt * 16 + lg * 4) * 2) ^ ((lr & 7) << 4);
    *(ushort4*)(Ep + byt) = ov.s4;
  }
  asm volatile("s_waitcnt lgkmcnt(0)" ::: "memory");
  const int lane2 = lr + lg * 16;
  const int ql = lane2 >> 2, c = lane2 & 3;
  #pragma unroll
  for (int s = 0; s < 2; ++s) {
    int byt = (ql * 128 + (c * 16 + s * 8) * 2) ^ ((ql & 7) << 4);
    bf16x8 vrow = *(const bf16x8*)(Ep + byt);
    *(bf16x8*)(attout + (size_t)(bb * S_LEN + q0 + ql) * EMB + h * HD + c * 16 + s * 8) = vrow;
  }
}

extern "C" void kernel_launch(void* const* d_in, const int* in_sizes, int n_in,
                              void* d_out, int out_size, void* d_ws, size_t ws_size,
                              hipStream_t stream) {
  const float* x     = (const float*)d_in[0];
  const float* Wqkv  = (const float*)d_in[1];
  const float* bqkv  = (const float*)d_in[2];
  const float* Wproj = (const float*)d_in[3];
  const float* bproj = (const float*)d_in[4];

  unsigned short* WqkvT  = (unsigned short*)d_ws;                  // 3072*1024
  unsigned short* WprojT = WqkvT  + (size_t)3 * EMB * EMB;         // 1024*1024
  unsigned short* qkv    = WprojT + (size_t)EMB * EMB;             // Q,K (b,h,s,d); V^T (b,h,d,s)
  unsigned short* att    = qkv    + 3ull * QSZ;                    // 4096*1024

  prep<<<dim3(4096), dim3(256), 0, stream>>>(Wqkv, Wproj, WqkvT, WprojT);

  gemm_qkv<<<dim3(M_TOT / 128, 3 * EMB / 128), dim3(512), 0, stream>>>(
      x, WqkvT, bqkv, qkv);

  attn_fwd<<<dim3(16 * BATCH * NH), dim3(256), 0, stream>>>(
      qkv, qkv + QSZ, qkv + 2ull * QSZ, att);

  gemm_proj<<<dim3(M_TOT / 128, EMB / 64), dim3(512), 0, stream>>>(
      att, WprojT, bproj, (float*)d_out);
}

// Round 19
// 81.994 us; speedup vs baseline: 1.1425x; 1.1338x over previous
//
#include <hip/hip_runtime.h>

#define S_LEN 1024
#define EMB   1024
#define NH    16
#define HD    64
#define BATCH 4
#define M_TOT 4096                 // BATCH * S_LEN
#define QSZ   (BATCH * NH * S_LEN * HD)   // 4194304 elems per Q/K/V tensor

typedef __attribute__((ext_vector_type(4))) float  f32x4;
typedef __attribute__((ext_vector_type(8))) __bf16 bf16x8;

__device__ __forceinline__ unsigned short f2bf(float f) {
  union { float f; unsigned u; } a; a.f = f;
  unsigned r = a.u + 0x7fffu + ((a.u >> 16) & 1u);   // RNE
  return (unsigned short)(r >> 16);
}

__device__ __forceinline__ float fexp2(float x) {
#if __has_builtin(__builtin_amdgcn_exp2f)
  return __builtin_amdgcn_exp2f(x);
#else
  return exp2f(x);
#endif
}

// ---------- fused prep: x->bf16 + Wqkv^T->bf16 + Wproj^T->bf16 ----------
__global__ __launch_bounds__(256) void prep(
    const float* __restrict__ x, const float* __restrict__ Wqkv,
    const float* __restrict__ Wproj,
    unsigned short* __restrict__ xb, unsigned short* __restrict__ WqkvT,
    unsigned short* __restrict__ WprojT)
{
  __shared__ unsigned short tile[32][33];
  const int bid = blockIdx.x;
  if (bid < 4096) {
    const int i = bid * 256 + threadIdx.x;
    float4 v = ((const float4*)x)[i];
    ushort4 o;
    o.x = f2bf(v.x); o.y = f2bf(v.y); o.z = f2bf(v.z); o.w = f2bf(v.w);
    ((ushort4*)xb)[i] = o;
    return;
  }
  const float* in; unsigned short* out; int N, n0, k0;
  if (bid < 7168) {
    const int b2 = bid - 4096;
    in = Wqkv; out = WqkvT; N = 3 * EMB;
    n0 = (b2 % 96) * 32; k0 = (b2 / 96) * 32;
  } else {
    const int b3 = bid - 7168;
    in = Wproj; out = WprojT; N = EMB;
    n0 = (b3 % 32) * 32; k0 = (b3 / 32) * 32;
  }
  const int tx = threadIdx.x & 31, ty = threadIdx.x >> 5;
  #pragma unroll
  for (int r = ty; r < 32; r += 8)
    tile[r][tx] = f2bf(in[(size_t)(k0 + r) * N + n0 + tx]);
  __syncthreads();
  #pragma unroll
  for (int r = ty; r < 32; r += 8)
    out[(size_t)(n0 + r) * EMB + k0 + tx] = tile[tx][r];
}

// ========== gemm1: 128x128 tile, 8 waves (2Mx4N), BK=64 (best: R13) ======
__global__ __launch_bounds__(512, 4) void gemm_qkv(
    const unsigned short* __restrict__ A,
    const unsigned short* __restrict__ Bt,
    const float* __restrict__ bias,
    unsigned short* __restrict__ O)
{
  __shared__ alignas(16) char smem[65536];   // [buf][A 16K | B 16K]
  const int m0 = blockIdx.x * 128, n0 = blockIdx.y * 128;
  const int K = EMB;
  const int t = threadIdx.x;
  const int wid = t >> 6, lane = t & 63;
  const int wm = wid >> 2, wn = wid & 3;     // 2 x 4 waves
  const int lr = lane & 15, lg = lane >> 4;
  const int nkt = K >> 6;

  f32x4 acc[4][2] = {};

  auto STAGE = [&](int b, int kt) {
    const int k0 = kt << 6;
    #pragma unroll
    for (int l = 0; l < 2; ++l) {
      const int L = l * 8192 + t * 16;
      const int row = L >> 7, c = (L >> 4) & 7;
      const int ce = (c ^ (row & 7)) << 3;
      const unsigned short* gA = A  + (size_t)(m0 + row) * K + k0 + ce;
      const unsigned short* gB = Bt + (size_t)(n0 + row) * K + k0 + ce;
      __builtin_amdgcn_global_load_lds(
          (const __attribute__((address_space(1))) unsigned int*)gA,
          (__attribute__((address_space(3))) unsigned int*)(smem + b * 32768 + L),
          16, 0, 0);
      __builtin_amdgcn_global_load_lds(
          (const __attribute__((address_space(1))) unsigned int*)gB,
          (__attribute__((address_space(3))) unsigned int*)(smem + b * 32768 + 16384 + L),
          16, 0, 0);
    }
  };

  STAGE(0, 0);

  for (int kt = 0; kt < nkt; ++kt) {
    const int cur = kt & 1;
    if (kt + 1 < nkt) {
      STAGE(cur ^ 1, kt + 1);
      asm volatile("s_waitcnt vmcnt(4)" ::: "memory");   // tile kt landed
    } else {
      asm volatile("s_waitcnt vmcnt(0)" ::: "memory");
    }
    __builtin_amdgcn_s_barrier();
    asm volatile("" ::: "memory");

    const char* Ab = smem + cur * 32768;
    const char* Bb = Ab + 16384;
    bf16x8 af[4][2], bfr[2][2];
    #pragma unroll
    for (int i = 0; i < 4; ++i)
      #pragma unroll
      for (int kk = 0; kk < 2; ++kk) {
        const int row = wm * 64 + i * 16 + lr;
        af[i][kk] = *(const bf16x8*)(Ab + row * 128 + (((kk * 4 + lg) ^ (row & 7)) << 4));
      }
    #pragma unroll
    for (int j = 0; j < 2; ++j)
      #pragma unroll
      for (int kk = 0; kk < 2; ++kk) {
        const int row = wn * 32 + j * 16 + lr;
        bfr[j][kk] = *(const bf16x8*)(Bb + row * 128 + (((kk * 4 + lg) ^ (row & 7)) << 4));
      }
    __builtin_amdgcn_s_setprio(1);
    #pragma unroll
    for (int i = 0; i < 4; ++i)
      #pragma unroll
      for (int j = 0; j < 2; ++j)
        #pragma unroll
        for (int kk = 0; kk < 2; ++kk)
          acc[i][j] = __builtin_amdgcn_mfma_f32_16x16x32_bf16(af[i][kk], bfr[j][kk], acc[i][j], 0, 0, 0);
    __builtin_amdgcn_s_setprio(0);

    asm volatile("s_waitcnt lgkmcnt(0)" ::: "memory");
    __builtin_amdgcn_s_barrier();
  }

  const int sec = n0 >> 10;                  // block-uniform: 0=Q 1=K 2=V
  if (sec < 2) {
    #pragma unroll
    for (int i = 0; i < 4; ++i)
      #pragma unroll
      for (int j = 0; j < 2; ++j) {
        const int col = n0 + wn * 32 + j * 16 + lr;
        const float bv = bias[col];
        const int cc = col & 1023, h = cc >> 6, d = cc & 63;
        #pragma unroll
        for (int r = 0; r < 4; ++r) {
          const int row = m0 + wm * 64 + i * 16 + lg * 4 + r;
          float v = acc[i][j][r] + bv;
          if (sec == 0) v *= 0.18033688f;    // 0.125 * log2(e)
          const int bb = row >> 10, ss = row & 1023;
          O[(size_t)sec * QSZ + (((size_t)(bb * NH + h) * S_LEN + ss) * HD + d)] = f2bf(v);
        }
      }
  } else {
    // V: transpose 128x128 tile through LDS, write V^T (b,h,d,s)
    unsigned short* T = (unsigned short*)smem;           // [128][136]
    #pragma unroll
    for (int i = 0; i < 4; ++i)
      #pragma unroll
      for (int j = 0; j < 2; ++j) {
        const int ci = wn * 32 + j * 16 + lr;            // col in tile
        const float bv = bias[n0 + ci];
        union { ushort4 s4; __bf16 b[4]; } pk;
        #pragma unroll
        for (int r = 0; r < 4; ++r) pk.b[r] = (__bf16)(acc[i][j][r] + bv);
        *(ushort4*)(T + ci * 136 + wm * 64 + i * 16 + lg * 4) = pk.s4;
      }
    __syncthreads();
    const int ci = t >> 2, part = t & 3;
    const int cc = (n0 - 2048) + ci;
    const int h = cc >> 6, d = cc & 63;
    const int bb2 = m0 >> 10, sbase = m0 & 1023;
    unsigned short* dst = O + 2ull * QSZ +
        ((size_t)(bb2 * NH + h) * HD + d) * S_LEN + sbase;
    #pragma unroll
    for (int u = 0; u < 4; ++u) {
      const int spos = part * 32 + u * 8;
      *(bf16x8*)(dst + spos) = *(const bf16x8*)(T + ci * 136 + spos);
    }
  }
}

// ========== gemm2 (proj): 128x64 tile, 8 waves (4Mx2N), BK=64 (R15) ======
__global__ __launch_bounds__(512, 4) void gemm_proj(
    const unsigned short* __restrict__ A,
    const unsigned short* __restrict__ Bt,
    const float* __restrict__ bias,
    float* __restrict__ Of)
{
  __shared__ alignas(16) char smem[49152];   // 2 bufs x (A 16K | B 8K)
  const int m0 = blockIdx.x * 128, n0 = blockIdx.y * 64;
  const int K = EMB;
  const int t = threadIdx.x;
  const int wid = t >> 6, lane = t & 63;
  const int wm = wid >> 1, wn = wid & 1;     // 4M x 2N waves, 32x32 each
  const int lr = lane & 15, lg = lane >> 4;
  const int nkt = K >> 6;                    // 16

  f32x4 acc[2][2] = {};

  auto STAGE = [&](int b, int kt) {
    const int k0 = kt << 6;
    char* dst = smem + b * 24576;
    #pragma unroll
    for (int l = 0; l < 2; ++l) {            // A: 16KB (128 rows x 128B)
      const int L = l * 8192 + t * 16;
      const int row = L >> 7, c = (L >> 4) & 7;
      const int ce = (c ^ (row & 7)) << 3;
      const unsigned short* gA = A + (size_t)(m0 + row) * K + k0 + ce;
      __builtin_amdgcn_global_load_lds(
          (const __attribute__((address_space(1))) unsigned int*)gA,
          (__attribute__((address_space(3))) unsigned int*)(dst + L),
          16, 0, 0);
    }
    {                                        // B: 8KB (64 rows x 128B)
      const int L = t * 16;
      const int row = L >> 7, c = (L >> 4) & 7;
      const int ce = (c ^ (row & 7)) << 3;
      const unsigned short* gB = Bt + (size_t)(n0 + row) * K + k0 + ce;
      __builtin_amdgcn_global_load_lds(
          (const __attribute__((address_space(1))) unsigned int*)gB,
          (__attribute__((address_space(3))) unsigned int*)(dst + 16384 + L),
          16, 0, 0);
    }
  };

  STAGE(0, 0);

  for (int kt = 0; kt < nkt; ++kt) {
    const int cur = kt & 1;
    if (kt + 1 < nkt) {
      STAGE(cur ^ 1, kt + 1);
      asm volatile("s_waitcnt vmcnt(3)" ::: "memory");   // tile kt landed
    } else {
      asm volatile("s_waitcnt vmcnt(0)" ::: "memory");
    }
    __builtin_amdgcn_s_barrier();
    asm volatile("" ::: "memory");

    const char* Ab = smem + cur * 24576;
    const char* Bb = Ab + 16384;
    bf16x8 af[2][2], bfr[2][2];
    #pragma unroll
    for (int i = 0; i < 2; ++i)
      #pragma unroll
      for (int kk = 0; kk < 2; ++kk) {
        const int row = wm * 32 + i * 16 + lr;
        af[i][kk] = *(const bf16x8*)(Ab + row * 128 + (((kk * 4 + lg) ^ (row & 7)) << 4));
      }
    #pragma unroll
    for (int j = 0; j < 2; ++j)
      #pragma unroll
      for (int kk = 0; kk < 2; ++kk) {
        const int row = wn * 32 + j * 16 + lr;
        bfr[j][kk] = *(const bf16x8*)(Bb + row * 128 + (((kk * 4 + lg) ^ (row & 7)) << 4));
      }
    __builtin_amdgcn_s_setprio(1);
    #pragma unroll
    for (int i = 0; i < 2; ++i)
      #pragma unroll
      for (int j = 0; j < 2; ++j)
        #pragma unroll
        for (int kk = 0; kk < 2; ++kk)
          acc[i][j] = __builtin_amdgcn_mfma_f32_16x16x32_bf16(af[i][kk], bfr[j][kk], acc[i][j], 0, 0, 0);
    __builtin_amdgcn_s_setprio(0);

    asm volatile("s_waitcnt lgkmcnt(0)" ::: "memory");
    __builtin_amdgcn_s_barrier();
  }

  #pragma unroll
  for (int i = 0; i < 2; ++i)
    #pragma unroll
    for (int j = 0; j < 2; ++j) {
      const int col = n0 + wn * 32 + j * 16 + lr;
      const float bv = bias[col];
      #pragma unroll
      for (int r = 0; r < 4; ++r) {
        const int row = m0 + wm * 32 + i * 16 + lg * 4 + r;
        Of[(size_t)row * EMB + col] = acc[i][j][r] + bv;
      }
    }
}

// ---------------- causal flash attention (R16 config) -------------------
__device__ __forceinline__ void group_tile(
    const char* sb, const bf16x8 (&kf)[8], const bf16x8 (&qf)[2],
    int kt, int q0, bool diag, int lr, int lg,
    float& m, float& lp, f32x4 (&o)[4])
{
  f32x4 sacc[4] = {};
  __builtin_amdgcn_s_setprio(1);
  #pragma unroll
  for (int nt = 0; nt < 4; ++nt)
    #pragma unroll
    for (int kk = 0; kk < 2; ++kk)
      sacc[nt] = __builtin_amdgcn_mfma_f32_16x16x32_bf16(kf[nt * 2 + kk], qf[kk], sacc[nt], 0, 0, 0);
  __builtin_amdgcn_s_setprio(0);

  float p[16];
  if (diag) {
    const int q = q0 + lr;
    #pragma unroll
    for (int nt = 0; nt < 4; ++nt)
      #pragma unroll
      for (int r = 0; r < 4; ++r) {
        int k = kt * 64 + nt * 16 + lg * 4 + r;
        p[nt * 4 + r] = (k > q) ? -1e30f : sacc[nt][r];
      }
  } else {
    #pragma unroll
    for (int nt = 0; nt < 4; ++nt)
      #pragma unroll
      for (int r = 0; r < 4; ++r)
        p[nt * 4 + r] = sacc[nt][r];
  }

  float r8[8], r4[4];
  #pragma unroll
  for (int i = 0; i < 8; ++i) r8[i] = fmaxf(p[i], p[i + 8]);
  #pragma unroll
  for (int i = 0; i < 4; ++i) r4[i] = fmaxf(r8[i], r8[i + 4]);
  float pm = fmaxf(fmaxf(r4[0], r4[1]), fmaxf(r4[2], r4[3]));
  if (__any(pm > m + 11.5f)) {
    float px = fmaxf(pm, __shfl_xor(pm, 16, 64));
    px = fmaxf(px, __shfl_xor(px, 32, 64));
    float mn = fmaxf(m, px);
    float fs = fexp2(m - mn);
    lp *= fs;
    #pragma unroll
    for (int dt = 0; dt < 4; ++dt)
      #pragma unroll
      for (int r = 0; r < 4; ++r) o[dt][r] *= fs;
    m = mn;
  }
  #pragma unroll
  for (int i = 0; i < 16; ++i) p[i] = fexp2(p[i] - m);

  float s8[8], s4[4];
  #pragma unroll
  for (int i = 0; i < 8; ++i) s8[i] = p[i] + p[i + 8];
  #pragma unroll
  for (int i = 0; i < 4; ++i) s4[i] = s8[i] + s8[i + 4];
  lp += (s4[0] + s4[1]) + (s4[2] + s4[3]);

  union { unsigned u[8]; __bf16 b[16]; } W;
  #pragma unroll
  for (int i = 0; i < 16; ++i) W.b[i] = (__bf16)p[i];

  const int dl0 = ((2 * (lg & 1) + (lg >> 1)) * 16 + lr) << 2;
  const int dl1 = ((2 * ((lg & 1) ^ 1) + (lg >> 1)) * 16 + lr) << 2;
  const bool oddlg = (lg & 1) != 0;
  const bool hb    = (lg >> 1) != 0;
  union { unsigned u[4]; bf16x8 v; } T0, T1;
  #pragma unroll
  for (int kk = 0; kk < 2; ++kk) {
    #pragma unroll
    for (int c = 0; c < 2; ++c) {
      unsigned vlo = W.u[4 * kk + c];
      unsigned vhi = W.u[4 * kk + 2 + c];
      unsigned s0 = oddlg ? vhi : vlo;
      unsigned s1 = oddlg ? vlo : vhi;
      unsigned r0 = (unsigned)__builtin_amdgcn_ds_permute(dl0, (int)s0);
      unsigned r1 = (unsigned)__builtin_amdgcn_ds_permute(dl1, (int)s1);
      unsigned* T = kk ? T1.u : T0.u;
      T[c]     = hb ? r1 : r0;
      T[2 + c] = hb ? r0 : r1;
    }
  }

  // PV: stream V^T fragments from LDS (16 regs at a time, keeps VGPR low)
  __builtin_amdgcn_s_setprio(1);
  #pragma unroll
  for (int dt = 0; dt < 4; ++dt) {
    const int byt = (dt * 16 + lr) * 128;
    bf16x8 v0 = *(const bf16x8*)(sb + 8192 + byt + (((0 + lg) ^ (lr & 7)) << 4));
    bf16x8 v1 = *(const bf16x8*)(sb + 8192 + byt + (((4 + lg) ^ (lr & 7)) << 4));
    o[dt] = __builtin_amdgcn_mfma_f32_16x16x32_bf16(v0, T0.v, o[dt], 0, 0, 0);
    o[dt] = __builtin_amdgcn_mfma_f32_16x16x32_bf16(v1, T1.v, o[dt], 0, 0, 0);
  }
  __builtin_amdgcn_s_setprio(0);
}

__global__ __launch_bounds__(256, 4) void attn_fwd(
    const unsigned short* __restrict__ Q,
    const unsigned short* __restrict__ K,
    const unsigned short* __restrict__ Vt,
    unsigned short* __restrict__ attout)
{
  __shared__ alignas(16) char stage[2][16384];   // 2-buf: K 8KB | V^T 8KB
  __shared__ alignas(16) char Ep_lds[4][2048];
  const int bid = blockIdx.x;
  const int bh = ((bid & 7) << 3) | ((bid >> 3) & 7);   // head; 16 blocks/head on 1 XCD
  const int qt = 15 - (bid >> 6);                       // heavy chunks first
  const int wv = threadIdx.x >> 6, lane = threadIdx.x & 63;
  const int lr = lane & 15, lg = lane >> 4;
  const int q0 = qt * 64 + wv * 16;
  const int nkt = qt + 1;
  const unsigned short* Qb = Q  + (size_t)bh * (S_LEN * HD);
  const unsigned short* Kh = K  + (size_t)bh * (S_LEN * HD);
  const unsigned short* Vh = Vt + (size_t)bh * (HD * S_LEN);
  const int bb = bh >> 4, h = bh & 15;

  auto STAGE = [&](int b, int kt) {
    char* lb = &stage[b][0];
    #pragma unroll
    for (int j = 0; j < 4; ++j) {
      if (wv < 2) {
        int L = wv * 4096 + j * 1024 + lane * 16;
        int row = L >> 7, c = (L >> 4) & 7;
        const unsigned short* src = Kh + (size_t)(kt * 64 + row) * HD + ((c ^ (row & 7)) << 3);
        __builtin_amdgcn_global_load_lds(
            (const __attribute__((address_space(1))) unsigned int*)src,
            (__attribute__((address_space(3))) unsigned int*)(lb + wv * 4096 + j * 1024),
            16, 0, 0);
      } else {
        int L = (wv - 2) * 4096 + j * 1024 + lane * 16;
        int row = L >> 7, c = (L >> 4) & 7;
        const unsigned short* src = Vh + (size_t)row * S_LEN + kt * 64 + ((c ^ (row & 7)) << 3);
        __builtin_amdgcn_global_load_lds(
            (const __attribute__((address_space(1))) unsigned int*)src,
            (__attribute__((address_space(3))) unsigned int*)(lb + 8192 + (wv - 2) * 4096 + j * 1024),
            16, 0, 0);
      }
    }
  };

  bf16x8 qf[2];
  #pragma unroll
  for (int kk = 0; kk < 2; ++kk)
    qf[kk] = *(const bf16x8*)(Qb + (size_t)(q0 + lr) * HD + kk * 32 + lg * 8);

  float m = -1e30f, lp = 0.f;
  f32x4 o[4] = {};

  STAGE(0, 0);

  for (int kt = 0; kt < nkt; ++kt) {
    asm volatile("s_waitcnt vmcnt(0)" ::: "memory");     // tile kt landed
    __builtin_amdgcn_s_barrier();
    asm volatile("" ::: "memory");

    const char* sb = &stage[kt & 1][0];
    bf16x8 kf[8];
    #pragma unroll
    for (int nt = 0; nt < 4; ++nt)
      #pragma unroll
      for (int kk = 0; kk < 2; ++kk) {
        const int byt = (nt * 16 + lr) * 128 + ((((kk << 2) + lg) ^ (lr & 7)) << 4);
        kf[nt * 2 + kk] = *(const bf16x8*)(sb + byt);
      }
    if (kt + 1 < nkt) STAGE((kt + 1) & 1, kt + 1);       // other buffer

    group_tile(sb, kf, qf, kt, q0, kt == nkt - 1, lr, lg, m, lp, o);

    asm volatile("s_waitcnt lgkmcnt(0)" ::: "memory");   // my reads done
    __builtin_amdgcn_s_barrier();
  }

  // epilogue: O^T[d][q] -> LDS (swizzled) -> coalesced (q, d) stores
  float l2 = lp + __shfl_xor(lp, 16, 64);
  float l4 = l2 + __shfl_xor(l2, 32, 64);
  float rl = 1.0f / l4;
  char* Ep = &Ep_lds[wv][0];
  #pragma unroll
  for (int dt = 0; dt < 4; ++dt) {
    union { ushort4 s4; __bf16 b[4]; } ov;
    #pragma unroll
    for (int r = 0; r < 4; ++r) ov.b[r] = (__bf16)(o[dt][r] * rl);
    int byt = (lr * 128 + (dt * 16 + lg * 4) * 2) ^ ((lr & 7) << 4);
    *(ushort4*)(Ep + byt) = ov.s4;
  }
  asm volatile("s_waitcnt lgkmcnt(0)" ::: "memory");
  const int lane2 = lr + lg * 16;
  const int ql = lane2 >> 2, c = lane2 & 3;
  #pragma unroll
  for (int s = 0; s < 2; ++s) {
    int byt = (ql * 128 + (c * 16 + s * 8) * 2) ^ ((ql & 7) << 4);
    bf16x8 vrow = *(const bf16x8*)(Ep + byt);
    *(bf16x8*)(attout + (size_t)(bb * S_LEN + q0 + ql) * EMB + h * HD + c * 16 + s * 8) = vrow;
  }
}

extern "C" void kernel_launch(void* const* d_in, const int* in_sizes, int n_in,
                              void* d_out, int out_size, void* d_ws, size_t ws_size,
                              hipStream_t stream) {
  const float* x     = (const float*)d_in[0];
  const float* Wqkv  = (const float*)d_in[1];
  const float* bqkv  = (const float*)d_in[2];
  const float* Wproj = (const float*)d_in[3];
  const float* bproj = (const float*)d_in[4];

  unsigned short* xb     = (unsigned short*)d_ws;                  // 4096*1024 x bf16
  unsigned short* WqkvT  = xb     + (size_t)M_TOT * EMB;           // 3072*1024
  unsigned short* WprojT = WqkvT  + (size_t)3 * EMB * EMB;         // 1024*1024
  unsigned short* qkv    = WprojT + (size_t)EMB * EMB;             // Q,K (b,h,s,d); V^T (b,h,d,s)
  unsigned short* att    = qkv    + 3ull * QSZ;                    // 4096*1024

  prep<<<dim3(8192), dim3(256), 0, stream>>>(x, Wqkv, Wproj, xb, WqkvT, WprojT);

  gemm_qkv<<<dim3(M_TOT / 128, 3 * EMB / 128), dim3(512), 0, stream>>>(
      xb, WqkvT, bqkv, qkv);

  attn_fwd<<<dim3(16 * BATCH * NH), dim3(256), 0, stream>>>(
      qkv, qkv + QSZ, qkv + 2ull * QSZ, att);

  gemm_proj<<<dim3(M_TOT / 128, EMB / 64), dim3(512), 0, stream>>>(
      att, WprojT, bproj, (float*)d_out);
}

// Round 20
// 81.852 us; speedup vs baseline: 1.1444x; 1.0017x over previous
//
#include <hip/hip_runtime.h>

#define S_LEN 1024
#define EMB   1024
#define NH    16
#define HD    64
#define BATCH 4
#define M_TOT 4096                 // BATCH * S_LEN
#define QSZ   (BATCH * NH * S_LEN * HD)   // 4194304 elems per Q/K/V tensor

typedef __attribute__((ext_vector_type(4))) float  f32x4;
typedef __attribute__((ext_vector_type(8))) __bf16 bf16x8;

__device__ __forceinline__ unsigned short f2bf(float f) {
  union { float f; unsigned u; } a; a.f = f;
  unsigned r = a.u + 0x7fffu + ((a.u >> 16) & 1u);   // RNE
  return (unsigned short)(r >> 16);
}

__device__ __forceinline__ float fexp2(float x) {
#if __has_builtin(__builtin_amdgcn_exp2f)
  return __builtin_amdgcn_exp2f(x);
#else
  return exp2f(x);
#endif
}

// ---------- fused prep: x->bf16 + Wqkv^T->bf16 + Wproj^T->bf16 ----------
__global__ __launch_bounds__(256) void prep(
    const float* __restrict__ x, const float* __restrict__ Wqkv,
    const float* __restrict__ Wproj,
    unsigned short* __restrict__ xb, unsigned short* __restrict__ WqkvT,
    unsigned short* __restrict__ WprojT)
{
  __shared__ unsigned short tile[32][33];
  const int bid = blockIdx.x;
  if (bid < 4096) {
    const int i = bid * 256 + threadIdx.x;
    float4 v = ((const float4*)x)[i];
    ushort4 o;
    o.x = f2bf(v.x); o.y = f2bf(v.y); o.z = f2bf(v.z); o.w = f2bf(v.w);
    ((ushort4*)xb)[i] = o;
    return;
  }
  const float* in; unsigned short* out; int N, n0, k0;
  if (bid < 7168) {
    const int b2 = bid - 4096;
    in = Wqkv; out = WqkvT; N = 3 * EMB;
    n0 = (b2 % 96) * 32; k0 = (b2 / 96) * 32;
  } else {
    const int b3 = bid - 7168;
    in = Wproj; out = WprojT; N = EMB;
    n0 = (b3 % 32) * 32; k0 = (b3 / 32) * 32;
  }
  const int tx = threadIdx.x & 31, ty = threadIdx.x >> 5;
  #pragma unroll
  for (int r = ty; r < 32; r += 8)
    tile[r][tx] = f2bf(in[(size_t)(k0 + r) * N + n0 + tx]);
  __syncthreads();
  #pragma unroll
  for (int r = ty; r < 32; r += 8)
    out[(size_t)(n0 + r) * EMB + k0 + tx] = tile[tx][r];
}

// ========== gemm1: 128x128 tile, 8 waves (2Mx4N), BK=64 (best: R13) ======
__global__ __launch_bounds__(512, 4) void gemm_qkv(
    const unsigned short* __restrict__ A,
    const unsigned short* __restrict__ Bt,
    const float* __restrict__ bias,
    unsigned short* __restrict__ O)
{
  __shared__ alignas(16) char smem[65536];   // [buf][A 16K | B 16K]
  const int m0 = blockIdx.x * 128, n0 = blockIdx.y * 128;
  const int K = EMB;
  const int t = threadIdx.x;
  const int wid = t >> 6, lane = t & 63;
  const int wm = wid >> 2, wn = wid & 3;     // 2 x 4 waves
  const int lr = lane & 15, lg = lane >> 4;
  const int nkt = K >> 6;

  f32x4 acc[4][2] = {};

  auto STAGE = [&](int b, int kt) {
    const int k0 = kt << 6;
    #pragma unroll
    for (int l = 0; l < 2; ++l) {
      const int L = l * 8192 + t * 16;
      const int row = L >> 7, c = (L >> 4) & 7;
      const int ce = (c ^ (row & 7)) << 3;
      const unsigned short* gA = A  + (size_t)(m0 + row) * K + k0 + ce;
      const unsigned short* gB = Bt + (size_t)(n0 + row) * K + k0 + ce;
      __builtin_amdgcn_global_load_lds(
          (const __attribute__((address_space(1))) unsigned int*)gA,
          (__attribute__((address_space(3))) unsigned int*)(smem + b * 32768 + L),
          16, 0, 0);
      __builtin_amdgcn_global_load_lds(
          (const __attribute__((address_space(1))) unsigned int*)gB,
          (__attribute__((address_space(3))) unsigned int*)(smem + b * 32768 + 16384 + L),
          16, 0, 0);
    }
  };

  STAGE(0, 0);

  for (int kt = 0; kt < nkt; ++kt) {
    const int cur = kt & 1;
    if (kt + 1 < nkt) {
      STAGE(cur ^ 1, kt + 1);
      asm volatile("s_waitcnt vmcnt(4)" ::: "memory");   // tile kt landed
    } else {
      asm volatile("s_waitcnt vmcnt(0)" ::: "memory");
    }
    __builtin_amdgcn_s_barrier();
    asm volatile("" ::: "memory");

    const char* Ab = smem + cur * 32768;
    const char* Bb = Ab + 16384;
    bf16x8 af[4][2], bfr[2][2];
    #pragma unroll
    for (int i = 0; i < 4; ++i)
      #pragma unroll
      for (int kk = 0; kk < 2; ++kk) {
        const int row = wm * 64 + i * 16 + lr;
        af[i][kk] = *(const bf16x8*)(Ab + row * 128 + (((kk * 4 + lg) ^ (row & 7)) << 4));
      }
    #pragma unroll
    for (int j = 0; j < 2; ++j)
      #pragma unroll
      for (int kk = 0; kk < 2; ++kk) {
        const int row = wn * 32 + j * 16 + lr;
        bfr[j][kk] = *(const bf16x8*)(Bb + row * 128 + (((kk * 4 + lg) ^ (row & 7)) << 4));
      }
    __builtin_amdgcn_s_setprio(1);
    #pragma unroll
    for (int i = 0; i < 4; ++i)
      #pragma unroll
      for (int j = 0; j < 2; ++j)
        #pragma unroll
        for (int kk = 0; kk < 2; ++kk)
          acc[i][j] = __builtin_amdgcn_mfma_f32_16x16x32_bf16(af[i][kk], bfr[j][kk], acc[i][j], 0, 0, 0);
    __builtin_amdgcn_s_setprio(0);

    asm volatile("s_waitcnt lgkmcnt(0)" ::: "memory");
    __builtin_amdgcn_s_barrier();
  }

  const int sec = n0 >> 10;                  // block-uniform: 0=Q 1=K 2=V
  if (sec < 2) {
    #pragma unroll
    for (int i = 0; i < 4; ++i)
      #pragma unroll
      for (int j = 0; j < 2; ++j) {
        const int col = n0 + wn * 32 + j * 16 + lr;
        const float bv = bias[col];
        const int cc = col & 1023, h = cc >> 6, d = cc & 63;
        #pragma unroll
        for (int r = 0; r < 4; ++r) {
          const int row = m0 + wm * 64 + i * 16 + lg * 4 + r;
          float v = acc[i][j][r] + bv;
          if (sec == 0) v *= 0.18033688f;    // 0.125 * log2(e)
          const int bb = row >> 10, ss = row & 1023;
          O[(size_t)sec * QSZ + (((size_t)(bb * NH + h) * S_LEN + ss) * HD + d)] = f2bf(v);
        }
      }
  } else {
    // V: transpose 128x128 tile through LDS, write V^T (b,h,d,s)
    unsigned short* T = (unsigned short*)smem;           // [128][136]
    #pragma unroll
    for (int i = 0; i < 4; ++i)
      #pragma unroll
      for (int j = 0; j < 2; ++j) {
        const int ci = wn * 32 + j * 16 + lr;            // col in tile
        const float bv = bias[n0 + ci];
        union { ushort4 s4; __bf16 b[4]; } pk;
        #pragma unroll
        for (int r = 0; r < 4; ++r) pk.b[r] = (__bf16)(acc[i][j][r] + bv);
        *(ushort4*)(T + ci * 136 + wm * 64 + i * 16 + lg * 4) = pk.s4;
      }
    __syncthreads();
    const int ci = t >> 2, part = t & 3;
    const int cc = (n0 - 2048) + ci;
    const int h = cc >> 6, d = cc & 63;
    const int bb2 = m0 >> 10, sbase = m0 & 1023;
    unsigned short* dst = O + 2ull * QSZ +
        ((size_t)(bb2 * NH + h) * HD + d) * S_LEN + sbase;
    #pragma unroll
    for (int u = 0; u < 4; ++u) {
      const int spos = part * 32 + u * 8;
      *(bf16x8*)(dst + spos) = *(const bf16x8*)(T + ci * 136 + spos);
    }
  }
}

// ========== gemm2 (proj): 128x64 tile, 8 waves (4Mx2N), BK=64 (R15) ======
__global__ __launch_bounds__(512, 4) void gemm_proj(
    const unsigned short* __restrict__ A,
    const unsigned short* __restrict__ Bt,
    const float* __restrict__ bias,
    float* __restrict__ Of)
{
  __shared__ alignas(16) char smem[49152];   // 2 bufs x (A 16K | B 8K)
  const int m0 = blockIdx.x * 128, n0 = blockIdx.y * 64;
  const int K = EMB;
  const int t = threadIdx.x;
  const int wid = t >> 6, lane = t & 63;
  const int wm = wid >> 1, wn = wid & 1;     // 4M x 2N waves, 32x32 each
  const int lr = lane & 15, lg = lane >> 4;
  const int nkt = K >> 6;                    // 16

  f32x4 acc[2][2] = {};

  auto STAGE = [&](int b, int kt) {
    const int k0 = kt << 6;
    char* dst = smem + b * 24576;
    #pragma unroll
    for (int l = 0; l < 2; ++l) {            // A: 16KB (128 rows x 128B)
      const int L = l * 8192 + t * 16;
      const int row = L >> 7, c = (L >> 4) & 7;
      const int ce = (c ^ (row & 7)) << 3;
      const unsigned short* gA = A + (size_t)(m0 + row) * K + k0 + ce;
      __builtin_amdgcn_global_load_lds(
          (const __attribute__((address_space(1))) unsigned int*)gA,
          (__attribute__((address_space(3))) unsigned int*)(dst + L),
          16, 0, 0);
    }
    {                                        // B: 8KB (64 rows x 128B)
      const int L = t * 16;
      const int row = L >> 7, c = (L >> 4) & 7;
      const int ce = (c ^ (row & 7)) << 3;
      const unsigned short* gB = Bt + (size_t)(n0 + row) * K + k0 + ce;
      __builtin_amdgcn_global_load_lds(
          (const __attribute__((address_space(1))) unsigned int*)gB,
          (__attribute__((address_space(3))) unsigned int*)(dst + 16384 + L),
          16, 0, 0);
    }
  };

  STAGE(0, 0);

  for (int kt = 0; kt < nkt; ++kt) {
    const int cur = kt & 1;
    if (kt + 1 < nkt) {
      STAGE(cur ^ 1, kt + 1);
      asm volatile("s_waitcnt vmcnt(3)" ::: "memory");   // tile kt landed
    } else {
      asm volatile("s_waitcnt vmcnt(0)" ::: "memory");
    }
    __builtin_amdgcn_s_barrier();
    asm volatile("" ::: "memory");

    const char* Ab = smem + cur * 24576;
    const char* Bb = Ab + 16384;
    bf16x8 af[2][2], bfr[2][2];
    #pragma unroll
    for (int i = 0; i < 2; ++i)
      #pragma unroll
      for (int kk = 0; kk < 2; ++kk) {
        const int row = wm * 32 + i * 16 + lr;
        af[i][kk] = *(const bf16x8*)(Ab + row * 128 + (((kk * 4 + lg) ^ (row & 7)) << 4));
      }
    #pragma unroll
    for (int j = 0; j < 2; ++j)
      #pragma unroll
      for (int kk = 0; kk < 2; ++kk) {
        const int row = wn * 32 + j * 16 + lr;
        bfr[j][kk] = *(const bf16x8*)(Bb + row * 128 + (((kk * 4 + lg) ^ (row & 7)) << 4));
      }
    __builtin_amdgcn_s_setprio(1);
    #pragma unroll
    for (int i = 0; i < 2; ++i)
      #pragma unroll
      for (int j = 0; j < 2; ++j)
        #pragma unroll
        for (int kk = 0; kk < 2; ++kk)
          acc[i][j] = __builtin_amdgcn_mfma_f32_16x16x32_bf16(af[i][kk], bfr[j][kk], acc[i][j], 0, 0, 0);
    __builtin_amdgcn_s_setprio(0);

    asm volatile("s_waitcnt lgkmcnt(0)" ::: "memory");
    __builtin_amdgcn_s_barrier();
  }

  #pragma unroll
  for (int i = 0; i < 2; ++i)
    #pragma unroll
    for (int j = 0; j < 2; ++j) {
      const int col = n0 + wn * 32 + j * 16 + lr;
      const float bv = bias[col];
      #pragma unroll
      for (int r = 0; r < 4; ++r) {
        const int row = m0 + wm * 32 + i * 16 + lg * 4 + r;
        Of[(size_t)row * EMB + col] = acc[i][j][r] + bv;
      }
    }
}

// ---------------- causal flash attention (R16 + single-barrier loop) ----
// Trailing per-iteration barrier removed: WAR on buffer (kt+1)&1 is
// already closed by {each wave's lgkmcnt(0) at end of iter kt-1 ->
// join barrier at top of iter kt}; STAGE(kt+1) is issued after that
// barrier. One barrier per k-tile.
__device__ __forceinline__ void group_tile(
    const char* sb, const bf16x8 (&kf)[8], const bf16x8 (&qf)[2],
    int kt, int q0, bool diag, int lr, int lg,
    float& m, float& lp, f32x4 (&o)[4])
{
  f32x4 sacc[4] = {};
  __builtin_amdgcn_s_setprio(1);
  #pragma unroll
  for (int nt = 0; nt < 4; ++nt)
    #pragma unroll
    for (int kk = 0; kk < 2; ++kk)
      sacc[nt] = __builtin_amdgcn_mfma_f32_16x16x32_bf16(kf[nt * 2 + kk], qf[kk], sacc[nt], 0, 0, 0);
  __builtin_amdgcn_s_setprio(0);

  float p[16];
  if (diag) {
    const int q = q0 + lr;
    #pragma unroll
    for (int nt = 0; nt < 4; ++nt)
      #pragma unroll
      for (int r = 0; r < 4; ++r) {
        int k = kt * 64 + nt * 16 + lg * 4 + r;
        p[nt * 4 + r] = (k > q) ? -1e30f : sacc[nt][r];
      }
  } else {
    #pragma unroll
    for (int nt = 0; nt < 4; ++nt)
      #pragma unroll
      for (int r = 0; r < 4; ++r)
        p[nt * 4 + r] = sacc[nt][r];
  }

  float r8[8], r4[4];
  #pragma unroll
  for (int i = 0; i < 8; ++i) r8[i] = fmaxf(p[i], p[i + 8]);
  #pragma unroll
  for (int i = 0; i < 4; ++i) r4[i] = fmaxf(r8[i], r8[i + 4]);
  float pm = fmaxf(fmaxf(r4[0], r4[1]), fmaxf(r4[2], r4[3]));
  if (__any(pm > m + 11.5f)) {
    float px = fmaxf(pm, __shfl_xor(pm, 16, 64));
    px = fmaxf(px, __shfl_xor(px, 32, 64));
    float mn = fmaxf(m, px);
    float fs = fexp2(m - mn);
    lp *= fs;
    #pragma unroll
    for (int dt = 0; dt < 4; ++dt)
      #pragma unroll
      for (int r = 0; r < 4; ++r) o[dt][r] *= fs;
    m = mn;
  }
  #pragma unroll
  for (int i = 0; i < 16; ++i) p[i] = fexp2(p[i] - m);

  float s8[8], s4[4];
  #pragma unroll
  for (int i = 0; i < 8; ++i) s8[i] = p[i] + p[i + 8];
  #pragma unroll
  for (int i = 0; i < 4; ++i) s4[i] = s8[i] + s8[i + 4];
  lp += (s4[0] + s4[1]) + (s4[2] + s4[3]);

  union { unsigned u[8]; __bf16 b[16]; } W;
  #pragma unroll
  for (int i = 0; i < 16; ++i) W.b[i] = (__bf16)p[i];

  const int dl0 = ((2 * (lg & 1) + (lg >> 1)) * 16 + lr) << 2;
  const int dl1 = ((2 * ((lg & 1) ^ 1) + (lg >> 1)) * 16 + lr) << 2;
  const bool oddlg = (lg & 1) != 0;
  const bool hb    = (lg >> 1) != 0;
  union { unsigned u[4]; bf16x8 v; } T0, T1;
  #pragma unroll
  for (int kk = 0; kk < 2; ++kk) {
    #pragma unroll
    for (int c = 0; c < 2; ++c) {
      unsigned vlo = W.u[4 * kk + c];
      unsigned vhi = W.u[4 * kk + 2 + c];
      unsigned s0 = oddlg ? vhi : vlo;
      unsigned s1 = oddlg ? vlo : vhi;
      unsigned r0 = (unsigned)__builtin_amdgcn_ds_permute(dl0, (int)s0);
      unsigned r1 = (unsigned)__builtin_amdgcn_ds_permute(dl1, (int)s1);
      unsigned* T = kk ? T1.u : T0.u;
      T[c]     = hb ? r1 : r0;
      T[2 + c] = hb ? r0 : r1;
    }
  }

  // PV: stream V^T fragments from LDS (16 regs at a time, keeps VGPR low)
  __builtin_amdgcn_s_setprio(1);
  #pragma unroll
  for (int dt = 0; dt < 4; ++dt) {
    const int byt = (dt * 16 + lr) * 128;
    bf16x8 v0 = *(const bf16x8*)(sb + 8192 + byt + (((0 + lg) ^ (lr & 7)) << 4));
    bf16x8 v1 = *(const bf16x8*)(sb + 8192 + byt + (((4 + lg) ^ (lr & 7)) << 4));
    o[dt] = __builtin_amdgcn_mfma_f32_16x16x32_bf16(v0, T0.v, o[dt], 0, 0, 0);
    o[dt] = __builtin_amdgcn_mfma_f32_16x16x32_bf16(v1, T1.v, o[dt], 0, 0, 0);
  }
  __builtin_amdgcn_s_setprio(0);
}

__global__ __launch_bounds__(256, 4) void attn_fwd(
    const unsigned short* __restrict__ Q,
    const unsigned short* __restrict__ K,
    const unsigned short* __restrict__ Vt,
    unsigned short* __restrict__ attout)
{
  __shared__ alignas(16) char stage[2][16384];   // 2-buf: K 8KB | V^T 8KB
  __shared__ alignas(16) char Ep_lds[4][2048];
  const int bid = blockIdx.x;
  const int bh = ((bid & 7) << 3) | ((bid >> 3) & 7);   // head; 16 blocks/head on 1 XCD
  const int qt = 15 - (bid >> 6);                       // heavy chunks first
  const int wv = threadIdx.x >> 6, lane = threadIdx.x & 63;
  const int lr = lane & 15, lg = lane >> 4;
  const int q0 = qt * 64 + wv * 16;
  const int nkt = qt + 1;
  const unsigned short* Qb = Q  + (size_t)bh * (S_LEN * HD);
  const unsigned short* Kh = K  + (size_t)bh * (S_LEN * HD);
  const unsigned short* Vh = Vt + (size_t)bh * (HD * S_LEN);
  const int bb = bh >> 4, h = bh & 15;

  auto STAGE = [&](int b, int kt) {
    char* lb = &stage[b][0];
    #pragma unroll
    for (int j = 0; j < 4; ++j) {
      if (wv < 2) {
        int L = wv * 4096 + j * 1024 + lane * 16;
        int row = L >> 7, c = (L >> 4) & 7;
        const unsigned short* src = Kh + (size_t)(kt * 64 + row) * HD + ((c ^ (row & 7)) << 3);
        __builtin_amdgcn_global_load_lds(
            (const __attribute__((address_space(1))) unsigned int*)src,
            (__attribute__((address_space(3))) unsigned int*)(lb + wv * 4096 + j * 1024),
            16, 0, 0);
      } else {
        int L = (wv - 2) * 4096 + j * 1024 + lane * 16;
        int row = L >> 7, c = (L >> 4) & 7;
        const unsigned short* src = Vh + (size_t)row * S_LEN + kt * 64 + ((c ^ (row & 7)) << 3);
        __builtin_amdgcn_global_load_lds(
            (const __attribute__((address_space(1))) unsigned int*)src,
            (__attribute__((address_space(3))) unsigned int*)(lb + 8192 + (wv - 2) * 4096 + j * 1024),
            16, 0, 0);
      }
    }
  };

  bf16x8 qf[2];
  #pragma unroll
  for (int kk = 0; kk < 2; ++kk)
    qf[kk] = *(const bf16x8*)(Qb + (size_t)(q0 + lr) * HD + kk * 32 + lg * 8);

  float m = -1e30f, lp = 0.f;
  f32x4 o[4] = {};

  STAGE(0, 0);

  for (int kt = 0; kt < nkt; ++kt) {
    asm volatile("s_waitcnt vmcnt(0)" ::: "memory");     // tile kt landed
    __builtin_amdgcn_s_barrier();    // join: all waves' prior LDS reads done
    asm volatile("" ::: "memory");

    const char* sb = &stage[kt & 1][0];
    bf16x8 kf[8];
    #pragma unroll
    for (int nt = 0; nt < 4; ++nt)
      #pragma unroll
      for (int kk = 0; kk < 2; ++kk) {
        const int byt = (nt * 16 + lr) * 128 + ((((kk << 2) + lg) ^ (lr & 7)) << 4);
        kf[nt * 2 + kk] = *(const bf16x8*)(sb + byt);
      }
    if (kt + 1 < nkt) STAGE((kt + 1) & 1, kt + 1);       // safe: after join

    group_tile(sb, kf, qf, kt, q0, kt == nkt - 1, lr, lg, m, lp, o);

    asm volatile("s_waitcnt lgkmcnt(0)" ::: "memory");   // my reads done
    // (trailing barrier removed — next iteration's join barrier suffices)
  }

  // epilogue: O^T[d][q] -> LDS (swizzled) -> coalesced (q, d) stores
  float l2 = lp + __shfl_xor(lp, 16, 64);
  float l4 = l2 + __shfl_xor(l2, 32, 64);
  float rl = 1.0f / l4;
  char* Ep = &Ep_lds[wv][0];
  #pragma unroll
  for (int dt = 0; dt < 4; ++dt) {
    union { ushort4 s4; __bf16 b[4]; } ov;
    #pragma unroll
    for (int r = 0; r < 4; ++r) ov.b[r] = (__bf16)(o[dt][r] * rl);
    int byt = (lr * 128 + (dt * 16 + lg * 4) * 2) ^ ((lr & 7) << 4);
    *(ushort4*)(Ep + byt) = ov.s4;
  }
  asm volatile("s_waitcnt lgkmcnt(0)" ::: "memory");
  const int lane2 = lr + lg * 16;
  const int ql = lane2 >> 2, c = lane2 & 3;
  #pragma unroll
  for (int s = 0; s < 2; ++s) {
    int byt = (ql * 128 + (c * 16 + s * 8) * 2) ^ ((ql & 7) << 4);
    bf16x8 vrow = *(const bf16x8*)(Ep + byt);
    *(bf16x8*)(attout + (size_t)(bb * S_LEN + q0 + ql) * EMB + h * HD + c * 16 + s * 8) = vrow;
  }
}

extern "C" void kernel_launch(void* const* d_in, const int* in_sizes, int n_in,
                              void* d_out, int out_size, void* d_ws, size_t ws_size,
                              hipStream_t stream) {
  const float* x     = (const float*)d_in[0];
  const float* Wqkv  = (const float*)d_in[1];
  const float* bqkv  = (const float*)d_in[2];
  const float* Wproj = (const float*)d_in[3];
  const float* bproj = (const float*)d_in[4];

  unsigned short* xb     = (unsigned short*)d_ws;                  // 4096*1024 x bf16
  unsigned short* WqkvT  = xb     + (size_t)M_TOT * EMB;           // 3072*1024
  unsigned short* WprojT = WqkvT  + (size_t)3 * EMB * EMB;         // 1024*1024
  unsigned short* qkv    = WprojT + (size_t)EMB * EMB;             // Q,K (b,h,s,d); V^T (b,h,d,s)
  unsigned short* att    = qkv    + 3ull * QSZ;                    // 4096*1024

  prep<<<dim3(8192), dim3(256), 0, stream>>>(x, Wqkv, Wproj, xb, WqkvT, WprojT);

  gemm_qkv<<<dim3(M_TOT / 128, 3 * EMB / 128), dim3(512), 0, stream>>>(
      xb, WqkvT, bqkv, qkv);

  attn_fwd<<<dim3(16 * BATCH * NH), dim3(256), 0, stream>>>(
      qkv, qkv + QSZ, qkv + 2ull * QSZ, att);

  gemm_proj<<<dim3(M_TOT / 128, EMB / 64), dim3(512), 0, stream>>>(
      att, WprojT, bproj, (float*)d_out);
}